// Round 1
// baseline (5696.532 us; speedup 1.0000x reference)
//
#include <hip/hip_runtime.h>
#include <hip/hip_bf16.h>

// Problem constants
#define BATCH 4
#define SEQ   4096
#define LSEQ  512
#define DMODEL 1024
#define DFF_  4096
#define NHEAD 16
#define DK_   64

// ---------------- LayerNorm (ddof=1, alpha*(x-mean)/(std+eps)+beta) ----------------
__global__ __launch_bounds__(256) void ln_kernel(
    const float* __restrict__ x, const float* __restrict__ alpha,
    const float* __restrict__ beta, float* __restrict__ y)
{
  int row = blockIdx.x;
  const float* xr = x + (size_t)row * DMODEL;
  float* yr = y + (size_t)row * DMODEL;
  int t = threadIdx.x;
  float v0 = xr[t], v1 = xr[t + 256], v2 = xr[t + 512], v3 = xr[t + 768];
  float s = v0 + v1 + v2 + v3;
  float ss = v0 * v0 + v1 * v1 + v2 * v2 + v3 * v3;
  for (int off = 32; off >= 1; off >>= 1) {
    s += __shfl_xor(s, off);
    ss += __shfl_xor(ss, off);
  }
  __shared__ float sbuf[4], ssbuf[4];
  int w = t >> 6;
  if ((t & 63) == 0) { sbuf[w] = s; ssbuf[w] = ss; }
  __syncthreads();
  s = sbuf[0] + sbuf[1] + sbuf[2] + sbuf[3];
  ss = ssbuf[0] + ssbuf[1] + ssbuf[2] + ssbuf[3];
  float mean = s * (1.f / DMODEL);
  float var = (ss - mean * mean * DMODEL) * (1.f / (DMODEL - 1));
  var = fmaxf(var, 0.f);
  float inv = 1.f / (sqrtf(var) + 1e-6f);
  yr[t]       = alpha[t]       * (v0 - mean) * inv + beta[t];
  yr[t + 256] = alpha[t + 256] * (v1 - mean) * inv + beta[t + 256];
  yr[t + 512] = alpha[t + 512] * (v2 - mean) * inv + beta[t + 512];
  yr[t + 768] = alpha[t + 768] * (v3 - mean) * inv + beta[t + 768];
}

// ---------------- fp32 tiled GEMM: C = act(A[M,K] @ W[K,N] (+bias)) (+R) ----------------
// ACT: 0 = none, 1 = relu, 2 = relu + 1e-6
template <int ACT, bool BIAS, bool RESID>
__global__ __launch_bounds__(256) void gemm_f32(
    const float* __restrict__ A, const float* __restrict__ W,
    const float* __restrict__ bias, const float* __restrict__ R,
    float* __restrict__ C, int M, int N, int K)
{
  __shared__ float As[16][65];
  __shared__ float Ws[16][65];
  int t = threadIdx.x;
  int m0 = blockIdx.y * 64, n0 = blockIdx.x * 64;
  int tx = t & 15, ty = t >> 4;
  float acc[4][4] = {};
  int la_m = t >> 2;        // 0..63
  int la_k = (t & 3) * 4;   // 0,4,8,12
  int lw_n = t & 63;
  int lw_k = t >> 6;        // 0..3

  for (int k0 = 0; k0 < K; k0 += 16) {
    const float4 av = *(const float4*)&A[(size_t)(m0 + la_m) * K + k0 + la_k];
    As[la_k + 0][la_m] = av.x;
    As[la_k + 1][la_m] = av.y;
    As[la_k + 2][la_m] = av.z;
    As[la_k + 3][la_m] = av.w;
#pragma unroll
    for (int i = 0; i < 4; ++i)
      Ws[lw_k + i * 4][lw_n] = W[(size_t)(k0 + lw_k + i * 4) * N + n0 + lw_n];
    __syncthreads();
#pragma unroll
    for (int kk = 0; kk < 16; ++kk) {
      float a[4], b[4];
#pragma unroll
      for (int i = 0; i < 4; ++i) a[i] = As[kk][ty * 4 + i];
#pragma unroll
      for (int j = 0; j < 4; ++j) b[j] = Ws[kk][tx * 4 + j];
#pragma unroll
      for (int i = 0; i < 4; ++i)
#pragma unroll
        for (int j = 0; j < 4; ++j) acc[i][j] += a[i] * b[j];
    }
    __syncthreads();
  }
#pragma unroll
  for (int i = 0; i < 4; ++i) {
    int m = m0 + ty * 4 + i;
#pragma unroll
    for (int j = 0; j < 4; ++j) {
      int n = n0 + tx * 4 + j;
      float v = acc[i][j];
      if (BIAS) v += bias[n];
      if (ACT == 1) v = fmaxf(v, 0.f);
      if (ACT == 2) v = fmaxf(v, 0.f) + 1e-6f;
      if (RESID) v += R[(size_t)m * N + n];
      C[(size_t)m * N + n] = v;
    }
  }
}

// ---------------- KV state: kv[b,h,d,e] = sum_n K[b,n,h*64+d]*V[b,n,h*64+e]; ksum[b,h] ----------------
__global__ __launch_bounds__(256) void kv_kernel(
    const float* __restrict__ Kp, const float* __restrict__ Vp,
    float* __restrict__ kvout, float* __restrict__ ksum, int Ntok)
{
  int h = blockIdx.x, b = blockIdx.y;
  const float* Kb = Kp + (size_t)b * Ntok * DMODEL + h * DK_;
  const float* Vb = Vp + (size_t)b * Ntok * DMODEL + h * DK_;
  __shared__ float Ks[16][64], Vs[16][64];
  int t = threadIdx.x;
  int tx = t & 15, ty = t >> 4;
  int lc = t & 63, lr = t >> 6;  // load col (0..63), row base (0..3)
  float acc[4][4] = {};
  float kpart = 0.f;
  for (int n0 = 0; n0 < Ntok; n0 += 16) {
#pragma unroll
    for (int i = 0; i < 4; ++i) {
      float kval = Kb[(size_t)(n0 + lr + i * 4) * DMODEL + lc];
      Ks[lr + i * 4][lc] = kval;
      kpart += kval;
      Vs[lr + i * 4][lc] = Vb[(size_t)(n0 + lr + i * 4) * DMODEL + lc];
    }
    __syncthreads();
#pragma unroll
    for (int nn = 0; nn < 16; ++nn) {
      float a[4], bb[4];
#pragma unroll
      for (int i = 0; i < 4; ++i) a[i] = Ks[nn][ty * 4 + i];
#pragma unroll
      for (int j = 0; j < 4; ++j) bb[j] = Vs[nn][tx * 4 + j];
#pragma unroll
      for (int i = 0; i < 4; ++i)
#pragma unroll
        for (int j = 0; j < 4; ++j) acc[i][j] += a[i] * bb[j];
    }
    __syncthreads();
  }
  float* kvb = kvout + ((size_t)(b * NHEAD + h)) * DK_ * DK_;
#pragma unroll
  for (int i = 0; i < 4; ++i)
#pragma unroll
    for (int j = 0; j < 4; ++j)
      kvb[(ty * 4 + i) * DK_ + tx * 4 + j] = acc[i][j];
  for (int off = 32; off >= 1; off >>= 1) kpart += __shfl_xor(kpart, off);
  __shared__ float kred[4];
  if ((t & 63) == 0) kred[t >> 6] = kpart;
  __syncthreads();
  if (t == 0) ksum[b * NHEAD + h] = kred[0] + kred[1] + kred[2] + kred[3];
}

// ---------------- AO[b,n,h*64+e] = (sum_d Q[...,d]*kv[d][e]) / (qsum*ksum + 1e-6) ----------------
__global__ __launch_bounds__(256) void qk_kernel(
    const float* __restrict__ Qp, const float* __restrict__ kv,
    const float* __restrict__ ksum, float* __restrict__ AO, int Ntok)
{
  int h = blockIdx.y, b = blockIdx.z;
  int n0 = blockIdx.x * 64;
  __shared__ float kvs[64][64];
  int t = threadIdx.x;
  const float* kvb = kv + ((size_t)(b * NHEAD + h)) * DK_ * DK_;
  for (int i = t; i < 4096; i += 256) kvs[i >> 6][i & 63] = kvb[i];
  __syncthreads();
  float ks = ksum[b * NHEAD + h];
  int lane = t & 63, w = t >> 6;
  for (int r = 0; r < 16; ++r) {
    int n = n0 + w * 16 + r;
    float qd = Qp[((size_t)b * Ntok + n) * DMODEL + h * DK_ + lane];
    float qs = qd;
    for (int off = 32; off >= 1; off >>= 1) qs += __shfl_xor(qs, off);
    float rn = 1.f / (qs * ks + 1e-6f);
    float acc = 0.f;
#pragma unroll
    for (int d = 0; d < 64; ++d) acc += __shfl(qd, d) * kvs[d][lane];
    AO[((size_t)b * Ntok + n) * DMODEL + h * DK_ + lane] = acc * rn;
  }
}

extern "C" void kernel_launch(void* const* d_in, const int* in_sizes, int n_in,
                              void* d_out, int out_size, void* d_ws, size_t ws_size,
                              hipStream_t stream) {
  const float* x    = (const float*)d_in[0];
  const float* lto  = (const float*)d_in[1];
  const float* sa_wq = (const float*)d_in[4];
  const float* sa_wk = (const float*)d_in[5];
  const float* sa_wv = (const float*)d_in[6];
  const float* sa_wo = (const float*)d_in[7];
  const float* ca_wq = (const float*)d_in[8];
  const float* ca_wk = (const float*)d_in[9];
  const float* ca_wv = (const float*)d_in[10];
  const float* ca_wo = (const float*)d_in[11];
  const float* ff_w1 = (const float*)d_in[12];
  const float* ff_b1 = (const float*)d_in[13];
  const float* ff_w2 = (const float*)d_in[14];
  const float* ff_b2 = (const float*)d_in[15];
  const float* ln1_a = (const float*)d_in[16];
  const float* ln1_b = (const float*)d_in[17];
  const float* ln2_a = (const float*)d_in[18];
  const float* ln2_b = (const float*)d_in[19];
  const float* ln3_a = (const float*)d_in[20];
  const float* ln3_b = (const float*)d_in[21];
  float* out = (float*)d_out;

  const size_t SBIG = (size_t)BATCH * SEQ * DMODEL;      // 16,777,216
  const size_t SSML = (size_t)BATCH * LSEQ * DMODEL;     // 2,097,152
  float* ws = (float*)d_ws;
  float* BA   = ws;                 // xn -> X1 -> FF hidden
  float* BB   = ws + SBIG;          // K -> Q -> caK
  float* BC   = ws + 2 * SBIG;      // V -> AO -> caV
  float* LTON = ws + 3 * SBIG;
  float* CAQ  = LTON + SSML;
  float* CAO  = CAQ + SSML;
  float* LTO1 = CAO + SSML;
  float* FN   = LTO1 + SSML;
  float* KVB  = FN + SSML;          // 64*64*64 = 262,144
  float* KSUM = KVB + (size_t)BATCH * NHEAD * DK_ * DK_; // 64

  const int STOK = BATCH * SEQ;   // 16384
  const int LTOK = BATCH * LSEQ;  // 2048
  dim3 blk(256);

  // ---- Phase A: self attention on x ----
  ln_kernel<<<STOK, blk, 0, stream>>>(x, ln1_a, ln1_b, BA);
  gemm_f32<2, false, false><<<dim3(16, 256), blk, 0, stream>>>(BA, sa_wk, nullptr, nullptr, BB, STOK, DMODEL, DMODEL); // K
  gemm_f32<0, false, false><<<dim3(16, 256), blk, 0, stream>>>(BA, sa_wv, nullptr, nullptr, BC, STOK, DMODEL, DMODEL); // V
  kv_kernel<<<dim3(NHEAD, BATCH), blk, 0, stream>>>(BB, BC, KVB, KSUM, SEQ);
  gemm_f32<2, false, false><<<dim3(16, 256), blk, 0, stream>>>(BA, sa_wq, nullptr, nullptr, BB, STOK, DMODEL, DMODEL); // Q (overwrites K)
  qk_kernel<<<dim3(SEQ / 64, NHEAD, BATCH), blk, 0, stream>>>(BB, KVB, KSUM, BC, SEQ);                                 // AO (overwrites V)
  gemm_f32<0, false, true><<<dim3(16, 256), blk, 0, stream>>>(BC, sa_wo, nullptr, x, BA, STOK, DMODEL, DMODEL);        // X1 = x + AO@wo

  // ---- Phase B: cross attention (Q from lto, K/V from X1) ----
  ln_kernel<<<LTOK, blk, 0, stream>>>(lto, ln2_a, ln2_b, LTON);
  gemm_f32<2, false, false><<<dim3(16, 32), blk, 0, stream>>>(LTON, ca_wq, nullptr, nullptr, CAQ, LTOK, DMODEL, DMODEL);
  gemm_f32<2, false, false><<<dim3(16, 256), blk, 0, stream>>>(BA, ca_wk, nullptr, nullptr, BB, STOK, DMODEL, DMODEL); // caK
  gemm_f32<0, false, false><<<dim3(16, 256), blk, 0, stream>>>(BA, ca_wv, nullptr, nullptr, BC, STOK, DMODEL, DMODEL); // caV
  kv_kernel<<<dim3(NHEAD, BATCH), blk, 0, stream>>>(BB, BC, KVB, KSUM, SEQ);
  qk_kernel<<<dim3(LSEQ / 64, NHEAD, BATCH), blk, 0, stream>>>(CAQ, KVB, KSUM, CAO, LSEQ);
  gemm_f32<0, false, true><<<dim3(16, 32), blk, 0, stream>>>(CAO, ca_wo, nullptr, lto, LTO1, LTOK, DMODEL, DMODEL);    // LTO1

  // ---- Phase C: feed forward ----
  ln_kernel<<<LTOK, blk, 0, stream>>>(LTO1, ln3_a, ln3_b, FN);
  gemm_f32<1, true, false><<<dim3(64, 32), blk, 0, stream>>>(FN, ff_w1, ff_b1, nullptr, BA, LTOK, DFF_, DMODEL);       // FF hidden (reuses BA)
  gemm_f32<0, true, true><<<dim3(16, 32), blk, 0, stream>>>(BA, ff_w2, ff_b2, LTO1, out, LTOK, DMODEL, DFF_);          // out = LTO1 + ...
}

// Round 2
// 932.707 us; speedup vs baseline: 6.1075x; 6.1075x over previous
//
#include <hip/hip_runtime.h>
#include <hip/hip_bf16.h>

#define BATCH 4
#define SEQ   4096
#define LSEQ  512
#define DMODEL 1024
#define DFF_  4096
#define NHEAD 16
#define DK_   64
#define NSPLIT 8

typedef __attribute__((ext_vector_type(4))) float f32x4;
typedef __attribute__((ext_vector_type(8))) __bf16 bf16x8;
typedef __attribute__((ext_vector_type(8))) unsigned short ushort8v;
typedef unsigned short u16;

__device__ __forceinline__ u16 f2bf(float f) {
  union { float f; unsigned int u; } c; c.f = f;
  unsigned int u = c.u;
  u += 0x7fffu + ((u >> 16) & 1u);
  return (u16)(u >> 16);
}
__device__ __forceinline__ float bf2f(u16 h) {
  union { unsigned int u; float f; } c; c.u = ((unsigned int)h) << 16;
  return c.f;
}
__device__ __forceinline__ void gload16(const void* g, void* l) {
  __builtin_amdgcn_global_load_lds(
      (const __attribute__((address_space(1))) unsigned int*)g,
      (__attribute__((address_space(3))) unsigned int*)l, 16, 0, 0);
}

// ---------------- LayerNorm (ddof=1, alpha*(x-mean)/(std+eps)+beta) -> bf16 ----------------
__global__ __launch_bounds__(256) void ln_kernel(
    const float* __restrict__ x, const float* __restrict__ alpha,
    const float* __restrict__ beta, u16* __restrict__ y)
{
  int row = blockIdx.x;
  const float* xr = x + (size_t)row * DMODEL;
  u16* yr = y + (size_t)row * DMODEL;
  int t = threadIdx.x;
  float v0 = xr[t], v1 = xr[t + 256], v2 = xr[t + 512], v3 = xr[t + 768];
  float s = v0 + v1 + v2 + v3;
  float ss = v0 * v0 + v1 * v1 + v2 * v2 + v3 * v3;
  for (int off = 32; off >= 1; off >>= 1) {
    s += __shfl_xor(s, off);
    ss += __shfl_xor(ss, off);
  }
  __shared__ float sbuf[4], ssbuf[4];
  int w = t >> 6;
  if ((t & 63) == 0) { sbuf[w] = s; ssbuf[w] = ss; }
  __syncthreads();
  s = sbuf[0] + sbuf[1] + sbuf[2] + sbuf[3];
  ss = ssbuf[0] + ssbuf[1] + ssbuf[2] + ssbuf[3];
  float mean = s * (1.f / DMODEL);
  float var = (ss - mean * mean * DMODEL) * (1.f / (DMODEL - 1));
  var = fmaxf(var, 0.f);
  float inv = 1.f / (sqrtf(var) + 1e-6f);
  yr[t]       = f2bf(alpha[t]       * (v0 - mean) * inv + beta[t]);
  yr[t + 256] = f2bf(alpha[t + 256] * (v1 - mean) * inv + beta[t + 256]);
  yr[t + 512] = f2bf(alpha[t + 512] * (v2 - mean) * inv + beta[t + 512]);
  yr[t + 768] = f2bf(alpha[t + 768] * (v3 - mean) * inv + beta[t + 768]);
}

// ---------------- transpose-convert W[K,N] f32 -> Wt[N,K] bf16 ----------------
__global__ __launch_bounds__(256) void wconv_t_kernel(
    const float* __restrict__ W, u16* __restrict__ Wt, int K, int N)
{
  __shared__ float tile[32][33];
  const int n0 = blockIdx.x * 32, k0 = blockIdx.y * 32;
  const int t = threadIdx.x;
  const int r = t >> 3, c4 = (t & 7) * 4;
  float4 v = *(const float4*)&W[(size_t)(k0 + r) * N + n0 + c4];
  tile[r][c4 + 0] = v.x; tile[r][c4 + 1] = v.y;
  tile[r][c4 + 2] = v.z; tile[r][c4 + 3] = v.w;
  __syncthreads();
  ushort4 o;
  o.x = f2bf(tile[c4 + 0][r]);
  o.y = f2bf(tile[c4 + 1][r]);
  o.z = f2bf(tile[c4 + 2][r]);
  o.w = f2bf(tile[c4 + 3][r]);
  *(ushort4*)&Wt[(size_t)(n0 + r) * K + k0 + c4] = o;
}

// ---------------- bf16 MFMA GEMM: C = act(A[M,K] @ Bt[N,K]^T (+bias)) (+R) ----------------
// ACT: 0 none, 1 relu, 2 relu+1e-6.  OUTBF: write bf16 else fp32.
template <int ACT, bool BIAS, bool RESID, bool OUTBF>
__global__ __launch_bounds__(256) void gemm_bf16(
    const u16* __restrict__ A, const u16* __restrict__ Bt,
    const float* __restrict__ bias, const float* __restrict__ R,
    void* __restrict__ Cout, int M, int N, int K)
{
  __shared__ u16 As[128 * 32];
  __shared__ u16 Bs[128 * 32];
  const int t = threadIdx.x;
  const int m0 = blockIdx.y * 128, n0 = blockIdx.x * 128;
  const int lane = t & 63, wid = t >> 6;
  const int wm = (wid >> 1) * 64, wn = (wid & 1) * 64;
  const int fr = lane & 15, fg = lane >> 4;

  const int srow = t >> 2;        // 0..63
  const int scol = (t & 3) * 8;   // element offset in 32-wide K-tile
  const u16* aptr = A + (size_t)(m0 + srow) * K + scol;
  const u16* bptr = Bt + (size_t)(n0 + srow) * K + scol;
  u16* adst0 = As + wid * 512;
  u16* adst1 = As + 2048 + wid * 512;
  u16* bdst0 = Bs + wid * 512;
  u16* bdst1 = Bs + 2048 + wid * 512;
  const size_t rstep = (size_t)64 * K;

  f32x4 acc[4][4] = {};

  for (int k0 = 0; k0 < K; k0 += 32) {
    gload16(aptr + k0, adst0);
    gload16(aptr + k0 + rstep, adst1);
    gload16(bptr + k0, bdst0);
    gload16(bptr + k0 + rstep, bdst1);
    __syncthreads();
    bf16x8 af[4], bfr[4];
#pragma unroll
    for (int mi = 0; mi < 4; ++mi)
      af[mi] = *(const bf16x8*)&As[(wm + mi * 16 + fr) * 32 + fg * 8];
#pragma unroll
    for (int ni = 0; ni < 4; ++ni)
      bfr[ni] = *(const bf16x8*)&Bs[(wn + ni * 16 + fr) * 32 + fg * 8];
#pragma unroll
    for (int mi = 0; mi < 4; ++mi)
#pragma unroll
      for (int ni = 0; ni < 4; ++ni)
        acc[mi][ni] = __builtin_amdgcn_mfma_f32_16x16x32_bf16(af[mi], bfr[ni], acc[mi][ni], 0, 0, 0);
    __syncthreads();
  }

  float* Cf = (float*)Cout;
  u16* Cb = (u16*)Cout;
#pragma unroll
  for (int mi = 0; mi < 4; ++mi)
#pragma unroll
    for (int ni = 0; ni < 4; ++ni)
#pragma unroll
      for (int r = 0; r < 4; ++r) {
        int row = m0 + wm + mi * 16 + fg * 4 + r;
        int col = n0 + wn + ni * 16 + fr;
        float v = acc[mi][ni][r];
        if (BIAS) v += bias[col];
        if (ACT == 1) v = fmaxf(v, 0.f);
        if (ACT == 2) v = fmaxf(v, 0.f) + 1e-6f;
        if (RESID) v += R[(size_t)row * N + col];
        if (OUTBF) Cb[(size_t)row * N + col] = f2bf(v);
        else       Cf[(size_t)row * N + col] = v;
      }
}

// ---------------- partial KV state over an n-chunk (bf16 in, f32 out) ----------------
__global__ __launch_bounds__(256) void kv_part_kernel(
    const u16* __restrict__ Kp, const u16* __restrict__ Vp,
    float* __restrict__ kvpart, float* __restrict__ kpart, int Ntok)
{
  const int h = blockIdx.x, b = blockIdx.y, sp = blockIdx.z;
  const int rows = Ntok / NSPLIT;
  const int nbeg = sp * rows;
  const u16* Kb = Kp + ((size_t)b * Ntok + nbeg) * DMODEL + h * DK_;
  const u16* Vb = Vp + ((size_t)b * Ntok + nbeg) * DMODEL + h * DK_;
  __shared__ float Ks[64][65];
  __shared__ float Vs[64][65];
  const int t = threadIdx.x;
  const int tx = t & 15, ty = t >> 4;
  const int lr = t >> 3;        // 0..31
  const int lc = (t & 7) * 8;   // 0..56
  float acc[4][4] = {};
  float kp = 0.f;
  for (int n0 = 0; n0 < rows; n0 += 64) {
#pragma unroll
    for (int p = 0; p < 2; ++p) {
      int r = p * 32 + lr;
      ushort8v k8 = *(const ushort8v*)&Kb[(size_t)(n0 + r) * DMODEL + lc];
      ushort8v v8 = *(const ushort8v*)&Vb[(size_t)(n0 + r) * DMODEL + lc];
#pragma unroll
      for (int i = 0; i < 8; ++i) {
        float kf = bf2f(k8[i]);
        Ks[r][lc + i] = kf;
        kp += kf;
        Vs[r][lc + i] = bf2f(v8[i]);
      }
    }
    __syncthreads();
    for (int nn = 0; nn < 64; ++nn) {
      float a[4], bb[4];
#pragma unroll
      for (int i = 0; i < 4; ++i) a[i] = Ks[nn][ty * 4 + i];
#pragma unroll
      for (int j = 0; j < 4; ++j) bb[j] = Vs[nn][tx * 4 + j];
#pragma unroll
      for (int i = 0; i < 4; ++i)
#pragma unroll
        for (int j = 0; j < 4; ++j) acc[i][j] += a[i] * bb[j];
    }
    __syncthreads();
  }
  float* outp = kvpart + (((size_t)(b * NHEAD + h)) * NSPLIT + sp) * (DK_ * DK_);
#pragma unroll
  for (int i = 0; i < 4; ++i)
#pragma unroll
    for (int j = 0; j < 4; ++j)
      outp[(ty * 4 + i) * DK_ + tx * 4 + j] = acc[i][j];
  for (int off = 32; off >= 1; off >>= 1) kp += __shfl_xor(kp, off);
  __shared__ float kr[4];
  if ((t & 63) == 0) kr[t >> 6] = kp;
  __syncthreads();
  if (t == 0) kpart[(b * NHEAD + h) * NSPLIT + sp] = kr[0] + kr[1] + kr[2] + kr[3];
}

__global__ __launch_bounds__(256) void kv_reduce_kernel(
    const float* __restrict__ kvpart, const float* __restrict__ kpart,
    float* __restrict__ kv, float* __restrict__ ksum)
{
  const int bh = blockIdx.x;
  const int t = threadIdx.x;
  for (int i = t; i < DK_ * DK_; i += 256) {
    float s = 0.f;
#pragma unroll
    for (int p = 0; p < NSPLIT; ++p)
      s += kvpart[((size_t)bh * NSPLIT + p) * (DK_ * DK_) + i];
    kv[(size_t)bh * (DK_ * DK_) + i] = s;
  }
  if (t == 0) {
    float s = 0.f;
    for (int p = 0; p < NSPLIT; ++p) s += kpart[bh * NSPLIT + p];
    ksum[bh] = s;
  }
}

// ---------------- AO = (Q @ kv) * 1/(qsum*ksum+1e-6), bf16 in/out ----------------
__global__ __launch_bounds__(256) void qk_kernel(
    const u16* __restrict__ Qp, const float* __restrict__ kv,
    const float* __restrict__ ksum, u16* __restrict__ AO, int Ntok)
{
  const int h = blockIdx.y, b = blockIdx.z;
  const int n0 = blockIdx.x * 64;
  __shared__ float kvs[64][65];
  const int t = threadIdx.x;
  const float* kvb = kv + ((size_t)(b * NHEAD + h)) * (DK_ * DK_);
  for (int i = t; i < DK_ * DK_; i += 256) kvs[i >> 6][i & 63] = kvb[i];
  __syncthreads();
  const float ks = ksum[b * NHEAD + h];
  const int lane = t & 63, w = t >> 6;
  for (int r = 0; r < 16; ++r) {
    int n = n0 + w * 16 + r;
    float qd = bf2f(Qp[((size_t)b * Ntok + n) * DMODEL + h * DK_ + lane]);
    float qs = qd;
    for (int off = 32; off >= 1; off >>= 1) qs += __shfl_xor(qs, off);
    float rn = 1.f / (qs * ks + 1e-6f);
    float acc = 0.f;
#pragma unroll
    for (int d = 0; d < 64; ++d) acc += __shfl(qd, d) * kvs[d][lane];
    AO[((size_t)b * Ntok + n) * DMODEL + h * DK_ + lane] = f2bf(acc * rn);
  }
}

extern "C" void kernel_launch(void* const* d_in, const int* in_sizes, int n_in,
                              void* d_out, int out_size, void* d_ws, size_t ws_size,
                              hipStream_t stream) {
  const float* x     = (const float*)d_in[0];
  const float* lto   = (const float*)d_in[1];
  const float* sa_wq = (const float*)d_in[4];
  const float* sa_wk = (const float*)d_in[5];
  const float* sa_wv = (const float*)d_in[6];
  const float* sa_wo = (const float*)d_in[7];
  const float* ca_wq = (const float*)d_in[8];
  const float* ca_wk = (const float*)d_in[9];
  const float* ca_wv = (const float*)d_in[10];
  const float* ca_wo = (const float*)d_in[11];
  const float* ff_w1 = (const float*)d_in[12];
  const float* ff_b1 = (const float*)d_in[13];
  const float* ff_w2 = (const float*)d_in[14];
  const float* ff_b2 = (const float*)d_in[15];
  const float* ln1_a = (const float*)d_in[16];
  const float* ln1_b = (const float*)d_in[17];
  const float* ln2_a = (const float*)d_in[18];
  const float* ln2_b = (const float*)d_in[19];
  const float* ln3_a = (const float*)d_in[20];
  const float* ln3_b = (const float*)d_in[21];
  float* out = (float*)d_out;

  char* wsb = (char*)d_ws;
  auto take = [&](size_t bytes) {
    char* p = wsb;
    wsb += (bytes + 255) & ~(size_t)255;
    return (void*)p;
  };
  u16* SAQT = (u16*)take(2097152);
  u16* SAKT = (u16*)take(2097152);
  u16* SAVT = (u16*)take(2097152);
  u16* SAOT = (u16*)take(2097152);
  u16* CQT  = (u16*)take(2097152);
  u16* CKT  = (u16*)take(2097152);
  u16* CVT  = (u16*)take(2097152);
  u16* COT  = (u16*)take(2097152);
  u16* FW1T = (u16*)take(8388608);
  u16* FW2T = (u16*)take(8388608);
  u16* R1 = (u16*)take(33554432);   // XN -> AO -> caV
  u16* R2 = (u16*)take(33554432);   // K -> Q -> caK -> FF hidden
  u16* R3 = (u16*)take(33554432);   // V -> X1
  u16* S1 = (u16*)take(4194304);    // LTON -> FN
  u16* S2 = (u16*)take(4194304);    // CAQ
  u16* S3 = (u16*)take(4194304);    // CAO
  float* LTO1   = (float*)take(8388608);
  float* KVPART = (float*)take(8388608);
  float* KVB    = (float*)take(1048576);
  float* KPART  = (float*)take(2048);
  float* KSUM   = (float*)take(256);

  const int STOK = BATCH * SEQ;   // 16384
  const int LTOK = BATCH * LSEQ;  // 2048
  dim3 blk(256);

  // ---- weight transpose-convert to bf16 [N,K] ----
  wconv_t_kernel<<<dim3(32, 32), blk, 0, stream>>>(sa_wq, SAQT, 1024, 1024);
  wconv_t_kernel<<<dim3(32, 32), blk, 0, stream>>>(sa_wk, SAKT, 1024, 1024);
  wconv_t_kernel<<<dim3(32, 32), blk, 0, stream>>>(sa_wv, SAVT, 1024, 1024);
  wconv_t_kernel<<<dim3(32, 32), blk, 0, stream>>>(sa_wo, SAOT, 1024, 1024);
  wconv_t_kernel<<<dim3(32, 32), blk, 0, stream>>>(ca_wq, CQT, 1024, 1024);
  wconv_t_kernel<<<dim3(32, 32), blk, 0, stream>>>(ca_wk, CKT, 1024, 1024);
  wconv_t_kernel<<<dim3(32, 32), blk, 0, stream>>>(ca_wv, CVT, 1024, 1024);
  wconv_t_kernel<<<dim3(32, 32), blk, 0, stream>>>(ca_wo, COT, 1024, 1024);
  wconv_t_kernel<<<dim3(128, 32), blk, 0, stream>>>(ff_w1, FW1T, 1024, 4096);
  wconv_t_kernel<<<dim3(32, 128), blk, 0, stream>>>(ff_w2, FW2T, 4096, 1024);

  // ---- Phase A: self attention ----
  ln_kernel<<<STOK, blk, 0, stream>>>(x, ln1_a, ln1_b, R1);
  gemm_bf16<2, false, false, true><<<dim3(8, 128), blk, 0, stream>>>(R1, SAKT, nullptr, nullptr, R2, STOK, 1024, 1024); // K
  gemm_bf16<0, false, false, true><<<dim3(8, 128), blk, 0, stream>>>(R1, SAVT, nullptr, nullptr, R3, STOK, 1024, 1024); // V
  kv_part_kernel<<<dim3(NHEAD, BATCH, NSPLIT), blk, 0, stream>>>(R2, R3, KVPART, KPART, SEQ);
  kv_reduce_kernel<<<64, blk, 0, stream>>>(KVPART, KPART, KVB, KSUM);
  gemm_bf16<2, false, false, true><<<dim3(8, 128), blk, 0, stream>>>(R1, SAQT, nullptr, nullptr, R2, STOK, 1024, 1024); // Q
  qk_kernel<<<dim3(SEQ / 64, NHEAD, BATCH), blk, 0, stream>>>(R2, KVB, KSUM, R1, SEQ);                                  // AO
  gemm_bf16<0, false, true, true><<<dim3(8, 128), blk, 0, stream>>>(R1, SAOT, nullptr, x, R3, STOK, 1024, 1024);        // X1 (bf16)

  // ---- Phase B: cross attention ----
  ln_kernel<<<LTOK, blk, 0, stream>>>(lto, ln2_a, ln2_b, S1);
  gemm_bf16<2, false, false, true><<<dim3(8, 16), blk, 0, stream>>>(S1, CQT, nullptr, nullptr, S2, LTOK, 1024, 1024);   // caQ
  gemm_bf16<2, false, false, true><<<dim3(8, 128), blk, 0, stream>>>(R3, CKT, nullptr, nullptr, R2, STOK, 1024, 1024);  // caK
  gemm_bf16<0, false, false, true><<<dim3(8, 128), blk, 0, stream>>>(R3, CVT, nullptr, nullptr, R1, STOK, 1024, 1024);  // caV
  kv_part_kernel<<<dim3(NHEAD, BATCH, NSPLIT), blk, 0, stream>>>(R2, R1, KVPART, KPART, SEQ);
  kv_reduce_kernel<<<64, blk, 0, stream>>>(KVPART, KPART, KVB, KSUM);
  qk_kernel<<<dim3(LSEQ / 64, NHEAD, BATCH), blk, 0, stream>>>(S2, KVB, KSUM, S3, LSEQ);                                // CAO
  gemm_bf16<0, false, true, false><<<dim3(8, 16), blk, 0, stream>>>(S3, COT, nullptr, lto, LTO1, LTOK, 1024, 1024);     // LTO1 fp32

  // ---- Phase C: feed forward ----
  ln_kernel<<<LTOK, blk, 0, stream>>>(LTO1, ln3_a, ln3_b, S1);
  gemm_bf16<1, true, false, true><<<dim3(32, 16), blk, 0, stream>>>(S1, FW1T, ff_b1, nullptr, R2, LTOK, 4096, 1024);    // FF hidden
  gemm_bf16<0, true, true, false><<<dim3(8, 16), blk, 0, stream>>>(R2, FW2T, ff_b2, LTO1, out, LTOK, 1024, 4096);       // out
}

// Round 3
// 723.310 us; speedup vs baseline: 7.8756x; 1.2895x over previous
//
#include <hip/hip_runtime.h>
#include <hip/hip_bf16.h>

#define BATCH 4
#define SEQ   4096
#define LSEQ  512
#define DMODEL 1024
#define DFF_  4096
#define NHEAD 16
#define DK_   64
#define NSPLIT 8

typedef __attribute__((ext_vector_type(4))) float f32x4;
typedef __attribute__((ext_vector_type(8))) __bf16 bf16x8;
typedef __attribute__((ext_vector_type(8))) unsigned short ushort8v;
typedef unsigned short u16;

__device__ __forceinline__ u16 f2bf(float f) {
  union { float f; unsigned int u; } c; c.f = f;
  unsigned int u = c.u;
  u += 0x7fffu + ((u >> 16) & 1u);
  return (u16)(u >> 16);
}
__device__ __forceinline__ float bf2f(u16 h) {
  union { unsigned int u; float f; } c; c.u = ((unsigned int)h) << 16;
  return c.f;
}
__device__ __forceinline__ void gload16(const void* g, void* l) {
  __builtin_amdgcn_global_load_lds(
      (const __attribute__((address_space(1))) unsigned int*)g,
      (__attribute__((address_space(3))) unsigned int*)l, 16, 0, 0);
}

// ---------------- LayerNorm (ddof=1, alpha*(x-mean)/(std+eps)+beta) -> bf16 ----------------
__global__ __launch_bounds__(256) void ln_kernel(
    const float* __restrict__ x, const float* __restrict__ alpha,
    const float* __restrict__ beta, u16* __restrict__ y)
{
  int row = blockIdx.x;
  const float* xr = x + (size_t)row * DMODEL;
  u16* yr = y + (size_t)row * DMODEL;
  int t = threadIdx.x;
  float v0 = xr[t], v1 = xr[t + 256], v2 = xr[t + 512], v3 = xr[t + 768];
  float s = v0 + v1 + v2 + v3;
  float ss = v0 * v0 + v1 * v1 + v2 * v2 + v3 * v3;
  for (int off = 32; off >= 1; off >>= 1) {
    s += __shfl_xor(s, off);
    ss += __shfl_xor(ss, off);
  }
  __shared__ float sbuf[4], ssbuf[4];
  int w = t >> 6;
  if ((t & 63) == 0) { sbuf[w] = s; ssbuf[w] = ss; }
  __syncthreads();
  s = sbuf[0] + sbuf[1] + sbuf[2] + sbuf[3];
  ss = ssbuf[0] + ssbuf[1] + ssbuf[2] + ssbuf[3];
  float mean = s * (1.f / DMODEL);
  float var = (ss - mean * mean * DMODEL) * (1.f / (DMODEL - 1));
  var = fmaxf(var, 0.f);
  float inv = 1.f / (sqrtf(var) + 1e-6f);
  yr[t]       = f2bf(alpha[t]       * (v0 - mean) * inv + beta[t]);
  yr[t + 256] = f2bf(alpha[t + 256] * (v1 - mean) * inv + beta[t + 256]);
  yr[t + 512] = f2bf(alpha[t + 512] * (v2 - mean) * inv + beta[t + 512]);
  yr[t + 768] = f2bf(alpha[t + 768] * (v3 - mean) * inv + beta[t + 768]);
}

// ---------------- transpose-convert W[K,N] f32 -> Wt[N,K] bf16 ----------------
__global__ __launch_bounds__(256) void wconv_t_kernel(
    const float* __restrict__ W, u16* __restrict__ Wt, int K, int N)
{
  __shared__ float tile[32][33];
  const int n0 = blockIdx.x * 32, k0 = blockIdx.y * 32;
  const int t = threadIdx.x;
  const int r = t >> 3, c4 = (t & 7) * 4;
  float4 v = *(const float4*)&W[(size_t)(k0 + r) * N + n0 + c4];
  tile[r][c4 + 0] = v.x; tile[r][c4 + 1] = v.y;
  tile[r][c4 + 2] = v.z; tile[r][c4 + 3] = v.w;
  __syncthreads();
  ushort4 o;
  o.x = f2bf(tile[c4 + 0][r]);
  o.y = f2bf(tile[c4 + 1][r]);
  o.z = f2bf(tile[c4 + 2][r]);
  o.w = f2bf(tile[c4 + 3][r]);
  *(ushort4*)&Wt[(size_t)(n0 + r) * K + k0 + c4] = o;
}

// ---------------- bf16 MFMA GEMM: C = act(A[M,K] @ Bt[N,K]^T (+bias)) (+R) ----------------
// ACT: 0 none, 1 relu, 2 relu+1e-6.  OUTBF: write bf16 else fp32.
template <int ACT, bool BIAS, bool RESID, bool OUTBF>
__global__ __launch_bounds__(256) void gemm_bf16(
    const u16* __restrict__ A, const u16* __restrict__ Bt,
    const float* __restrict__ bias, const float* __restrict__ R,
    void* __restrict__ Cout, int M, int N, int K)
{
  __shared__ u16 As[128 * 32];
  __shared__ u16 Bs[128 * 32];
  const int t = threadIdx.x;
  const int m0 = blockIdx.y * 128, n0 = blockIdx.x * 128;
  const int lane = t & 63, wid = t >> 6;
  const int wm = (wid >> 1) * 64, wn = (wid & 1) * 64;
  const int fr = lane & 15, fg = lane >> 4;

  const int srow = t >> 2;        // 0..63
  const int scol = (t & 3) * 8;   // element offset in 32-wide K-tile
  const u16* aptr = A + (size_t)(m0 + srow) * K + scol;
  const u16* bptr = Bt + (size_t)(n0 + srow) * K + scol;
  u16* adst0 = As + wid * 512;
  u16* adst1 = As + 2048 + wid * 512;
  u16* bdst0 = Bs + wid * 512;
  u16* bdst1 = Bs + 2048 + wid * 512;
  const size_t rstep = (size_t)64 * K;

  f32x4 acc[4][4] = {};

  for (int k0 = 0; k0 < K; k0 += 32) {
    gload16(aptr + k0, adst0);
    gload16(aptr + k0 + rstep, adst1);
    gload16(bptr + k0, bdst0);
    gload16(bptr + k0 + rstep, bdst1);
    __syncthreads();
    bf16x8 af[4], bfr[4];
#pragma unroll
    for (int mi = 0; mi < 4; ++mi)
      af[mi] = *(const bf16x8*)&As[(wm + mi * 16 + fr) * 32 + fg * 8];
#pragma unroll
    for (int ni = 0; ni < 4; ++ni)
      bfr[ni] = *(const bf16x8*)&Bs[(wn + ni * 16 + fr) * 32 + fg * 8];
#pragma unroll
    for (int mi = 0; mi < 4; ++mi)
#pragma unroll
      for (int ni = 0; ni < 4; ++ni)
        acc[mi][ni] = __builtin_amdgcn_mfma_f32_16x16x32_bf16(af[mi], bfr[ni], acc[mi][ni], 0, 0, 0);
    __syncthreads();
  }

  float* Cf = (float*)Cout;
  u16* Cb = (u16*)Cout;
#pragma unroll
  for (int mi = 0; mi < 4; ++mi)
#pragma unroll
    for (int ni = 0; ni < 4; ++ni)
#pragma unroll
      for (int r = 0; r < 4; ++r) {
        int row = m0 + wm + mi * 16 + fg * 4 + r;
        int col = n0 + wn + ni * 16 + fr;
        float v = acc[mi][ni][r];
        if (BIAS) v += bias[col];
        if (ACT == 1) v = fmaxf(v, 0.f);
        if (ACT == 2) v = fmaxf(v, 0.f) + 1e-6f;
        if (RESID) v += R[(size_t)row * N + col];
        if (OUTBF) Cb[(size_t)row * N + col] = f2bf(v);
        else       Cf[(size_t)row * N + col] = v;
      }
}

// ---------------- partial KV state over an n-chunk (bf16 in, f32 out) ----------------
__global__ __launch_bounds__(256) void kv_part_kernel(
    const u16* __restrict__ Kp, const u16* __restrict__ Vp,
    float* __restrict__ kvpart, float* __restrict__ kpart, int Ntok)
{
  const int h = blockIdx.x, b = blockIdx.y, sp = blockIdx.z;
  const int rows = Ntok / NSPLIT;
  const int nbeg = sp * rows;
  const u16* Kb = Kp + ((size_t)b * Ntok + nbeg) * DMODEL + h * DK_;
  const u16* Vb = Vp + ((size_t)b * Ntok + nbeg) * DMODEL + h * DK_;
  __shared__ float Ks[64][65];
  __shared__ float Vs[64][65];
  const int t = threadIdx.x;
  const int tx = t & 15, ty = t >> 4;
  const int lr = t >> 3;        // 0..31
  const int lc = (t & 7) * 8;   // 0..56
  float acc[4][4] = {};
  float kp = 0.f;
  for (int n0 = 0; n0 < rows; n0 += 64) {
#pragma unroll
    for (int p = 0; p < 2; ++p) {
      int r = p * 32 + lr;
      ushort8v k8 = *(const ushort8v*)&Kb[(size_t)(n0 + r) * DMODEL + lc];
      ushort8v v8 = *(const ushort8v*)&Vb[(size_t)(n0 + r) * DMODEL + lc];
#pragma unroll
      for (int i = 0; i < 8; ++i) {
        float kf = bf2f(k8[i]);
        Ks[r][lc + i] = kf;
        kp += kf;
        Vs[r][lc + i] = bf2f(v8[i]);
      }
    }
    __syncthreads();
    for (int nn = 0; nn < 64; ++nn) {
      float a[4], bb[4];
#pragma unroll
      for (int i = 0; i < 4; ++i) a[i] = Ks[nn][ty * 4 + i];
#pragma unroll
      for (int j = 0; j < 4; ++j) bb[j] = Vs[nn][tx * 4 + j];
#pragma unroll
      for (int i = 0; i < 4; ++i)
#pragma unroll
        for (int j = 0; j < 4; ++j) acc[i][j] += a[i] * bb[j];
    }
    __syncthreads();
  }
  float* outp = kvpart + (((size_t)(b * NHEAD + h)) * NSPLIT + sp) * (DK_ * DK_);
#pragma unroll
  for (int i = 0; i < 4; ++i)
#pragma unroll
    for (int j = 0; j < 4; ++j)
      outp[(ty * 4 + i) * DK_ + tx * 4 + j] = acc[i][j];
  for (int off = 32; off >= 1; off >>= 1) kp += __shfl_xor(kp, off);
  __shared__ float kr[4];
  if ((t & 63) == 0) kr[t >> 6] = kp;
  __syncthreads();
  if (t == 0) kpart[(b * NHEAD + h) * NSPLIT + sp] = kr[0] + kr[1] + kr[2] + kr[3];
}

// reduce partials -> kv^T bf16 [e][d] + ksum
__global__ __launch_bounds__(256) void kv_reduce_kernel(
    const float* __restrict__ kvpart, const float* __restrict__ kpart,
    u16* __restrict__ kvT, float* __restrict__ ksum)
{
  const int bh = blockIdx.x;
  const int t = threadIdx.x;
  for (int i = t; i < DK_ * DK_; i += 256) {
    int d = i >> 6, e = i & 63;
    float s = 0.f;
#pragma unroll
    for (int p = 0; p < NSPLIT; ++p)
      s += kvpart[((size_t)bh * NSPLIT + p) * (DK_ * DK_) + i];
    kvT[(size_t)bh * (DK_ * DK_) + e * DK_ + d] = f2bf(s);
  }
  if (t == 0) {
    float s = 0.f;
    for (int p = 0; p < NSPLIT; ++p) s += kpart[bh * NSPLIT + p];
    ksum[bh] = s;
  }
}

// ---------------- AO = (Q @ kv) * 1/(qsum*ksum+1e-6) via MFMA ----------------
// Q bf16 [Ntok, 1024] (head slice), kvT bf16 [e][d] per (b,h), AO bf16.
__global__ __launch_bounds__(256) void qk_mfma_kernel(
    const u16* __restrict__ Qp, const u16* __restrict__ kvT,
    const float* __restrict__ ksum, u16* __restrict__ AO, int Ntok)
{
  const int h = blockIdx.y, b = blockIdx.z;
  const int n0 = blockIdx.x * 128;
  const int t = threadIdx.x;
  const int lane = t & 63, wid = t >> 6;
  const int fr = lane & 15, fg = lane >> 4;

  __shared__ u16 Qs[128 * 64];    // swizzled rows of 128B
  __shared__ u16 KVs[64 * 64];    // kv^T, swizzled
  __shared__ float qsl[128];

  auto swz = [](int byte, int row) { return byte ^ ((row & 7) << 4); };

  // stage Q tile: 128 rows x 128B = 1024 chunks of 16B
  const u16* Qbase = Qp + ((size_t)b * Ntok + n0) * DMODEL + h * DK_;
#pragma unroll
  for (int j = 0; j < 4; ++j) {
    int id = t + 256 * j;
    int r = id >> 3, cseg = id & 7;
    ushort8v v = *(const ushort8v*)(Qbase + (size_t)r * DMODEL + cseg * 8);
    *(ushort8v*)((char*)Qs + swz(r * 128 + cseg * 16, r)) = v;
  }
  // stage kv^T: 64 rows x 128B = 512 chunks
  const u16* Kbase = kvT + ((size_t)(b * NHEAD + h)) * (DK_ * DK_);
#pragma unroll
  for (int j = 0; j < 2; ++j) {
    int id = t + 256 * j;
    int r = id >> 3, cseg = id & 7;
    ushort8v v = *(const ushort8v*)(Kbase + r * DK_ + cseg * 8);
    *(ushort8v*)((char*)KVs + swz(r * 128 + cseg * 16, r)) = v;
  }
  __syncthreads();

  // qsum per row (2 threads per row, 32 elems each)
  {
    int row = t >> 1, part = t & 1;
    float s = 0.f;
#pragma unroll
    for (int j = 0; j < 4; ++j) {
      bf16x8 v = *(const bf16x8*)((char*)Qs + swz(row * 128 + (part * 4 + j) * 16, row));
#pragma unroll
      for (int i = 0; i < 8; ++i) s += (float)v[i];
    }
    s += __shfl_xor(s, 1);
    if (part == 0) qsl[row] = s;
  }

  // MFMA: each wave: 32 rows x 64 cols
  const int wm = wid * 32;
  f32x4 acc[2][4] = {};
#pragma unroll
  for (int kk = 0; kk < 2; ++kk) {
    bf16x8 af[2], bfv[4];
#pragma unroll
    for (int mi = 0; mi < 2; ++mi) {
      int row = wm + mi * 16 + fr;
      af[mi] = *(const bf16x8*)((char*)Qs + swz(row * 128 + kk * 64 + fg * 16, row));
    }
#pragma unroll
    for (int ni = 0; ni < 4; ++ni) {
      int row = ni * 16 + fr;
      bfv[ni] = *(const bf16x8*)((char*)KVs + swz(row * 128 + kk * 64 + fg * 16, row));
    }
#pragma unroll
    for (int mi = 0; mi < 2; ++mi)
#pragma unroll
      for (int ni = 0; ni < 4; ++ni)
        acc[mi][ni] = __builtin_amdgcn_mfma_f32_16x16x32_bf16(af[mi], bfv[ni], acc[mi][ni], 0, 0, 0);
  }
  __syncthreads();

  const float ks = ksum[b * NHEAD + h];
  u16* AObase = AO + ((size_t)b * Ntok + n0) * DMODEL + h * DK_;
#pragma unroll
  for (int mi = 0; mi < 2; ++mi)
#pragma unroll
    for (int ni = 0; ni < 4; ++ni)
#pragma unroll
      for (int r = 0; r < 4; ++r) {
        int row = wm + mi * 16 + fg * 4 + r;
        int col = ni * 16 + fr;
        float rn = 1.f / (qsl[row] * ks + 1e-6f);
        AObase[(size_t)row * DMODEL + col] = f2bf(acc[mi][ni][r] * rn);
      }
}

extern "C" void kernel_launch(void* const* d_in, const int* in_sizes, int n_in,
                              void* d_out, int out_size, void* d_ws, size_t ws_size,
                              hipStream_t stream) {
  const float* x     = (const float*)d_in[0];
  const float* lto   = (const float*)d_in[1];
  const float* sa_wq = (const float*)d_in[4];
  const float* sa_wk = (const float*)d_in[5];
  const float* sa_wv = (const float*)d_in[6];
  const float* sa_wo = (const float*)d_in[7];
  const float* ca_wq = (const float*)d_in[8];
  const float* ca_wk = (const float*)d_in[9];
  const float* ca_wv = (const float*)d_in[10];
  const float* ca_wo = (const float*)d_in[11];
  const float* ff_w1 = (const float*)d_in[12];
  const float* ff_b1 = (const float*)d_in[13];
  const float* ff_w2 = (const float*)d_in[14];
  const float* ff_b2 = (const float*)d_in[15];
  const float* ln1_a = (const float*)d_in[16];
  const float* ln1_b = (const float*)d_in[17];
  const float* ln2_a = (const float*)d_in[18];
  const float* ln2_b = (const float*)d_in[19];
  const float* ln3_a = (const float*)d_in[20];
  const float* ln3_b = (const float*)d_in[21];
  float* out = (float*)d_out;

  char* wsb = (char*)d_ws;
  auto take = [&](size_t bytes) {
    char* p = wsb;
    wsb += (bytes + 255) & ~(size_t)255;
    return (void*)p;
  };
  u16* SAQT = (u16*)take(2097152);
  u16* SAKT = (u16*)take(2097152);
  u16* SAVT = (u16*)take(2097152);
  u16* SAOT = (u16*)take(2097152);
  u16* CQT  = (u16*)take(2097152);
  u16* CKT  = (u16*)take(2097152);
  u16* CVT  = (u16*)take(2097152);
  u16* COT  = (u16*)take(2097152);
  u16* FW1T = (u16*)take(8388608);
  u16* FW2T = (u16*)take(8388608);
  u16* R1 = (u16*)take(33554432);   // XN -> AO -> caV
  u16* R2 = (u16*)take(33554432);   // K -> Q -> caK -> FF hidden
  u16* R3 = (u16*)take(33554432);   // V -> X1
  u16* S1 = (u16*)take(4194304);    // LTON -> FN
  u16* S2 = (u16*)take(4194304);    // CAQ
  u16* S3 = (u16*)take(4194304);    // CAO
  float* LTO1   = (float*)take(8388608);
  float* KVPART = (float*)take(8388608);
  u16*   KVT    = (u16*)take(1048576);
  float* KPART  = (float*)take(2048);
  float* KSUM   = (float*)take(256);

  const int STOK = BATCH * SEQ;   // 16384
  const int LTOK = BATCH * LSEQ;  // 2048
  dim3 blk(256);

  // ---- weight transpose-convert to bf16 [N,K] ----
  wconv_t_kernel<<<dim3(32, 32), blk, 0, stream>>>(sa_wq, SAQT, 1024, 1024);
  wconv_t_kernel<<<dim3(32, 32), blk, 0, stream>>>(sa_wk, SAKT, 1024, 1024);
  wconv_t_kernel<<<dim3(32, 32), blk, 0, stream>>>(sa_wv, SAVT, 1024, 1024);
  wconv_t_kernel<<<dim3(32, 32), blk, 0, stream>>>(sa_wo, SAOT, 1024, 1024);
  wconv_t_kernel<<<dim3(32, 32), blk, 0, stream>>>(ca_wq, CQT, 1024, 1024);
  wconv_t_kernel<<<dim3(32, 32), blk, 0, stream>>>(ca_wk, CKT, 1024, 1024);
  wconv_t_kernel<<<dim3(32, 32), blk, 0, stream>>>(ca_wv, CVT, 1024, 1024);
  wconv_t_kernel<<<dim3(32, 32), blk, 0, stream>>>(ca_wo, COT, 1024, 1024);
  wconv_t_kernel<<<dim3(128, 32), blk, 0, stream>>>(ff_w1, FW1T, 1024, 4096);
  wconv_t_kernel<<<dim3(32, 128), blk, 0, stream>>>(ff_w2, FW2T, 4096, 1024);

  // ---- Phase A: self attention ----
  ln_kernel<<<STOK, blk, 0, stream>>>(x, ln1_a, ln1_b, R1);
  gemm_bf16<2, false, false, true><<<dim3(8, 128), blk, 0, stream>>>(R1, SAKT, nullptr, nullptr, R2, STOK, 1024, 1024); // K
  gemm_bf16<0, false, false, true><<<dim3(8, 128), blk, 0, stream>>>(R1, SAVT, nullptr, nullptr, R3, STOK, 1024, 1024); // V
  kv_part_kernel<<<dim3(NHEAD, BATCH, NSPLIT), blk, 0, stream>>>(R2, R3, KVPART, KPART, SEQ);
  kv_reduce_kernel<<<64, blk, 0, stream>>>(KVPART, KPART, KVT, KSUM);
  gemm_bf16<2, false, false, true><<<dim3(8, 128), blk, 0, stream>>>(R1, SAQT, nullptr, nullptr, R2, STOK, 1024, 1024); // Q
  qk_mfma_kernel<<<dim3(SEQ / 128, NHEAD, BATCH), blk, 0, stream>>>(R2, KVT, KSUM, R1, SEQ);                            // AO
  gemm_bf16<0, false, true, true><<<dim3(8, 128), blk, 0, stream>>>(R1, SAOT, nullptr, x, R3, STOK, 1024, 1024);        // X1 (bf16)

  // ---- Phase B: cross attention ----
  ln_kernel<<<LTOK, blk, 0, stream>>>(lto, ln2_a, ln2_b, S1);
  gemm_bf16<2, false, false, true><<<dim3(8, 16), blk, 0, stream>>>(S1, CQT, nullptr, nullptr, S2, LTOK, 1024, 1024);   // caQ
  gemm_bf16<2, false, false, true><<<dim3(8, 128), blk, 0, stream>>>(R3, CKT, nullptr, nullptr, R2, STOK, 1024, 1024);  // caK
  gemm_bf16<0, false, false, true><<<dim3(8, 128), blk, 0, stream>>>(R3, CVT, nullptr, nullptr, R1, STOK, 1024, 1024);  // caV
  kv_part_kernel<<<dim3(NHEAD, BATCH, NSPLIT), blk, 0, stream>>>(R2, R1, KVPART, KPART, SEQ);
  kv_reduce_kernel<<<64, blk, 0, stream>>>(KVPART, KPART, KVT, KSUM);
  qk_mfma_kernel<<<dim3(LSEQ / 128, NHEAD, BATCH), blk, 0, stream>>>(S2, KVT, KSUM, S3, LSEQ);                          // CAO
  gemm_bf16<0, false, true, false><<<dim3(8, 16), blk, 0, stream>>>(S3, COT, nullptr, lto, LTO1, LTOK, 1024, 1024);     // LTO1 fp32

  // ---- Phase C: feed forward ----
  ln_kernel<<<LTOK, blk, 0, stream>>>(LTO1, ln3_a, ln3_b, S1);
  gemm_bf16<1, true, false, true><<<dim3(32, 16), blk, 0, stream>>>(S1, FW1T, ff_b1, nullptr, R2, LTOK, 4096, 1024);    // FF hidden
  gemm_bf16<0, true, true, false><<<dim3(8, 16), blk, 0, stream>>>(R2, FW2T, ff_b2, LTO1, out, LTOK, 1024, 4096);       // out
}

// Round 4
// 691.707 us; speedup vs baseline: 8.2355x; 1.0457x over previous
//
#include <hip/hip_runtime.h>
#include <hip/hip_bf16.h>

#define BATCH 4
#define SEQ   4096
#define LSEQ  512
#define DMODEL 1024
#define DFF_  4096
#define NHEAD 16
#define DK_   64
#define NSPLIT 8

typedef __attribute__((ext_vector_type(4))) float f32x4;
typedef __attribute__((ext_vector_type(8))) __bf16 bf16x8;
typedef __attribute__((ext_vector_type(8))) unsigned short ushort8v;
typedef unsigned short u16;

__device__ __forceinline__ u16 f2bf(float f) {
  union { float f; unsigned int u; } c; c.f = f;
  unsigned int u = c.u;
  u += 0x7fffu + ((u >> 16) & 1u);
  return (u16)(u >> 16);
}
__device__ __forceinline__ float bf2f(u16 h) {
  union { unsigned int u; float f; } c; c.u = ((unsigned int)h) << 16;
  return c.f;
}
__device__ __forceinline__ void gload16(const void* g, void* l) {
  __builtin_amdgcn_global_load_lds(
      (const __attribute__((address_space(1))) unsigned int*)g,
      (__attribute__((address_space(3))) unsigned int*)l, 16, 0, 0);
}

// ---------------- LayerNorm (ddof=1, alpha*(x-mean)/(std+eps)+beta) -> bf16 ----------------
__global__ __launch_bounds__(256) void ln_kernel(
    const float* __restrict__ x, const float* __restrict__ alpha,
    const float* __restrict__ beta, u16* __restrict__ y)
{
  int row = blockIdx.x;
  const float* xr = x + (size_t)row * DMODEL;
  u16* yr = y + (size_t)row * DMODEL;
  int t = threadIdx.x;
  float v0 = xr[t], v1 = xr[t + 256], v2 = xr[t + 512], v3 = xr[t + 768];
  float s = v0 + v1 + v2 + v3;
  float ss = v0 * v0 + v1 * v1 + v2 * v2 + v3 * v3;
  for (int off = 32; off >= 1; off >>= 1) {
    s += __shfl_xor(s, off);
    ss += __shfl_xor(ss, off);
  }
  __shared__ float sbuf[4], ssbuf[4];
  int w = t >> 6;
  if ((t & 63) == 0) { sbuf[w] = s; ssbuf[w] = ss; }
  __syncthreads();
  s = sbuf[0] + sbuf[1] + sbuf[2] + sbuf[3];
  ss = ssbuf[0] + ssbuf[1] + ssbuf[2] + ssbuf[3];
  float mean = s * (1.f / DMODEL);
  float var = (ss - mean * mean * DMODEL) * (1.f / (DMODEL - 1));
  var = fmaxf(var, 0.f);
  float inv = 1.f / (sqrtf(var) + 1e-6f);
  yr[t]       = f2bf(alpha[t]       * (v0 - mean) * inv + beta[t]);
  yr[t + 256] = f2bf(alpha[t + 256] * (v1 - mean) * inv + beta[t + 256]);
  yr[t + 512] = f2bf(alpha[t + 512] * (v2 - mean) * inv + beta[t + 512]);
  yr[t + 768] = f2bf(alpha[t + 768] * (v3 - mean) * inv + beta[t + 768]);
}

// ---------------- transpose-convert W[K,N] f32 -> Wt[N,K] bf16 ----------------
__global__ __launch_bounds__(256) void wconv_t_kernel(
    const float* __restrict__ W, u16* __restrict__ Wt, int K, int N)
{
  __shared__ float tile[32][33];
  const int n0 = blockIdx.x * 32, k0 = blockIdx.y * 32;
  const int t = threadIdx.x;
  const int r = t >> 3, c4 = (t & 7) * 4;
  float4 v = *(const float4*)&W[(size_t)(k0 + r) * N + n0 + c4];
  tile[r][c4 + 0] = v.x; tile[r][c4 + 1] = v.y;
  tile[r][c4 + 2] = v.z; tile[r][c4 + 3] = v.w;
  __syncthreads();
  ushort4 o;
  o.x = f2bf(tile[c4 + 0][r]);
  o.y = f2bf(tile[c4 + 1][r]);
  o.z = f2bf(tile[c4 + 2][r]);
  o.w = f2bf(tile[c4 + 3][r]);
  *(ushort4*)&Wt[(size_t)(n0 + r) * K + k0 + c4] = o;
}

// ---------------- bf16 MFMA GEMM, 2-phase double-buffered (T3 minimum recipe) ----------------
// C = act(A[M,K] @ Bt[N,K]^T (+bias)) (+R).  ACT: 0 none, 1 relu, 2 relu+1e-6.
template <int ACT, bool BIAS, bool RESID, bool OUTBF>
__global__ __launch_bounds__(256) void gemm_bf16(
    const u16* __restrict__ A, const u16* __restrict__ Bt,
    const float* __restrict__ bias, const float* __restrict__ R,
    void* __restrict__ Cout, int M, int N, int K)
{
  __shared__ u16 As[2][128 * 32];
  __shared__ u16 Bs[2][128 * 32];
  const int t = threadIdx.x;
  const int m0 = blockIdx.y * 128, n0 = blockIdx.x * 128;
  const int lane = t & 63, wid = t >> 6;
  const int wm = (wid >> 1) * 64, wn = (wid & 1) * 64;
  const int fr = lane & 15, fg = lane >> 4;

  const int srow = t >> 2;        // 0..63
  const int scol = (t & 3) * 8;   // element offset in 32-wide K-tile
  const u16* aptr = A + (size_t)(m0 + srow) * K + scol;
  const u16* bptr = Bt + (size_t)(n0 + srow) * K + scol;
  const size_t rstep = (size_t)64 * K;

  f32x4 acc[4][4] = {};

  auto stage = [&](int c, int k0) {
    gload16(aptr + k0,         &As[c][wid * 512]);
    gload16(aptr + k0 + rstep, &As[c][2048 + wid * 512]);
    gload16(bptr + k0,         &Bs[c][wid * 512]);
    gload16(bptr + k0 + rstep, &Bs[c][2048 + wid * 512]);
  };
  auto compute = [&](int c) {
    bf16x8 af[4], bfr[4];
#pragma unroll
    for (int mi = 0; mi < 4; ++mi)
      af[mi] = *(const bf16x8*)&As[c][(wm + mi * 16 + fr) * 32 + fg * 8];
#pragma unroll
    for (int ni = 0; ni < 4; ++ni)
      bfr[ni] = *(const bf16x8*)&Bs[c][(wn + ni * 16 + fr) * 32 + fg * 8];
#pragma unroll
    for (int mi = 0; mi < 4; ++mi)
#pragma unroll
      for (int ni = 0; ni < 4; ++ni)
        acc[mi][ni] = __builtin_amdgcn_mfma_f32_16x16x32_bf16(af[mi], bfr[ni], acc[mi][ni], 0, 0, 0);
  };

  const int NT = K >> 5;
  stage(0, 0);
  asm volatile("s_waitcnt vmcnt(0)" ::: "memory");
  __builtin_amdgcn_s_barrier();
  int cur = 0;
  for (int kt = 0; kt < NT - 1; ++kt) {
    stage(cur ^ 1, (kt + 1) * 32);   // prefetch next tile (in flight during compute)
    compute(cur);
    asm volatile("s_waitcnt vmcnt(0)" ::: "memory");
    __builtin_amdgcn_s_barrier();
    cur ^= 1;
  }
  compute(cur);

  float* Cf = (float*)Cout;
  u16* Cb = (u16*)Cout;
#pragma unroll
  for (int mi = 0; mi < 4; ++mi)
#pragma unroll
    for (int ni = 0; ni < 4; ++ni)
#pragma unroll
      for (int r = 0; r < 4; ++r) {
        int row = m0 + wm + mi * 16 + fg * 4 + r;
        int col = n0 + wn + ni * 16 + fr;
        float v = acc[mi][ni][r];
        if (BIAS) v += bias[col];
        if (ACT == 1) v = fmaxf(v, 0.f);
        if (ACT == 2) v = fmaxf(v, 0.f) + 1e-6f;
        if (RESID) v += R[(size_t)row * N + col];
        if (OUTBF) Cb[(size_t)row * N + col] = f2bf(v);
        else       Cf[(size_t)row * N + col] = v;
      }
}

// ---------------- partial KV state over an n-chunk (bf16 in, f32 out) ----------------
__global__ __launch_bounds__(256) void kv_part_kernel(
    const u16* __restrict__ Kp, const u16* __restrict__ Vp,
    float* __restrict__ kvpart, float* __restrict__ kpart, int Ntok)
{
  const int h = blockIdx.x, b = blockIdx.y, sp = blockIdx.z;
  const int rows = Ntok / NSPLIT;
  const int nbeg = sp * rows;
  const u16* Kb = Kp + ((size_t)b * Ntok + nbeg) * DMODEL + h * DK_;
  const u16* Vb = Vp + ((size_t)b * Ntok + nbeg) * DMODEL + h * DK_;
  __shared__ float Ks[64][65];
  __shared__ float Vs[64][65];
  const int t = threadIdx.x;
  const int tx = t & 15, ty = t >> 4;
  const int lr = t >> 3;        // 0..31
  const int lc = (t & 7) * 8;   // 0..56
  float acc[4][4] = {};
  float kp = 0.f;
  for (int n0 = 0; n0 < rows; n0 += 64) {
#pragma unroll
    for (int p = 0; p < 2; ++p) {
      int r = p * 32 + lr;
      ushort8v k8 = *(const ushort8v*)&Kb[(size_t)(n0 + r) * DMODEL + lc];
      ushort8v v8 = *(const ushort8v*)&Vb[(size_t)(n0 + r) * DMODEL + lc];
#pragma unroll
      for (int i = 0; i < 8; ++i) {
        float kf = bf2f(k8[i]);
        Ks[r][lc + i] = kf;
        kp += kf;
        Vs[r][lc + i] = bf2f(v8[i]);
      }
    }
    __syncthreads();
    for (int nn = 0; nn < 64; ++nn) {
      float a[4], bb[4];
#pragma unroll
      for (int i = 0; i < 4; ++i) a[i] = Ks[nn][ty * 4 + i];
#pragma unroll
      for (int j = 0; j < 4; ++j) bb[j] = Vs[nn][tx * 4 + j];
#pragma unroll
      for (int i = 0; i < 4; ++i)
#pragma unroll
        for (int j = 0; j < 4; ++j) acc[i][j] += a[i] * bb[j];
    }
    __syncthreads();
  }
  float* outp = kvpart + (((size_t)(b * NHEAD + h)) * NSPLIT + sp) * (DK_ * DK_);
#pragma unroll
  for (int i = 0; i < 4; ++i)
#pragma unroll
    for (int j = 0; j < 4; ++j)
      outp[(ty * 4 + i) * DK_ + tx * 4 + j] = acc[i][j];
  for (int off = 32; off >= 1; off >>= 1) kp += __shfl_xor(kp, off);
  __shared__ float kr[4];
  if ((t & 63) == 0) kr[t >> 6] = kp;
  __syncthreads();
  if (t == 0) kpart[(b * NHEAD + h) * NSPLIT + sp] = kr[0] + kr[1] + kr[2] + kr[3];
}

// reduce partials -> kv^T bf16 [e][d] + ksum
__global__ __launch_bounds__(256) void kv_reduce_kernel(
    const float* __restrict__ kvpart, const float* __restrict__ kpart,
    u16* __restrict__ kvT, float* __restrict__ ksum)
{
  const int bh = blockIdx.x;
  const int t = threadIdx.x;
  for (int i = t; i < DK_ * DK_; i += 256) {
    int d = i >> 6, e = i & 63;
    float s = 0.f;
#pragma unroll
    for (int p = 0; p < NSPLIT; ++p)
      s += kvpart[((size_t)bh * NSPLIT + p) * (DK_ * DK_) + i];
    kvT[(size_t)bh * (DK_ * DK_) + e * DK_ + d] = f2bf(s);
  }
  if (t == 0) {
    float s = 0.f;
    for (int p = 0; p < NSPLIT; ++p) s += kpart[bh * NSPLIT + p];
    ksum[bh] = s;
  }
}

// ---------------- AO = (Q @ kv) * 1/(qsum*ksum+1e-6) via MFMA ----------------
__global__ __launch_bounds__(256) void qk_mfma_kernel(
    const u16* __restrict__ Qp, const u16* __restrict__ kvT,
    const float* __restrict__ ksum, u16* __restrict__ AO, int Ntok)
{
  const int h = blockIdx.y, b = blockIdx.z;
  const int n0 = blockIdx.x * 128;
  const int t = threadIdx.x;
  const int lane = t & 63, wid = t >> 6;
  const int fr = lane & 15, fg = lane >> 4;

  __shared__ u16 Qs[128 * 64];    // swizzled rows of 128B
  __shared__ u16 KVs[64 * 64];    // kv^T, swizzled
  __shared__ float qsl[128];

  auto swz = [](int byte, int row) { return byte ^ ((row & 7) << 4); };

  const u16* Qbase = Qp + ((size_t)b * Ntok + n0) * DMODEL + h * DK_;
#pragma unroll
  for (int j = 0; j < 4; ++j) {
    int id = t + 256 * j;
    int r = id >> 3, cseg = id & 7;
    ushort8v v = *(const ushort8v*)(Qbase + (size_t)r * DMODEL + cseg * 8);
    *(ushort8v*)((char*)Qs + swz(r * 128 + cseg * 16, r)) = v;
  }
  const u16* Kbase = kvT + ((size_t)(b * NHEAD + h)) * (DK_ * DK_);
#pragma unroll
  for (int j = 0; j < 2; ++j) {
    int id = t + 256 * j;
    int r = id >> 3, cseg = id & 7;
    ushort8v v = *(const ushort8v*)(Kbase + r * DK_ + cseg * 8);
    *(ushort8v*)((char*)KVs + swz(r * 128 + cseg * 16, r)) = v;
  }
  __syncthreads();

  {
    int row = t >> 1, part = t & 1;
    float s = 0.f;
#pragma unroll
    for (int j = 0; j < 4; ++j) {
      bf16x8 v = *(const bf16x8*)((char*)Qs + swz(row * 128 + (part * 4 + j) * 16, row));
#pragma unroll
      for (int i = 0; i < 8; ++i) s += (float)v[i];
    }
    s += __shfl_xor(s, 1);
    if (part == 0) qsl[row] = s;
  }

  const int wm = wid * 32;
  f32x4 acc[2][4] = {};
#pragma unroll
  for (int kk = 0; kk < 2; ++kk) {
    bf16x8 af[2], bfv[4];
#pragma unroll
    for (int mi = 0; mi < 2; ++mi) {
      int row = wm + mi * 16 + fr;
      af[mi] = *(const bf16x8*)((char*)Qs + swz(row * 128 + kk * 64 + fg * 16, row));
    }
#pragma unroll
    for (int ni = 0; ni < 4; ++ni) {
      int row = ni * 16 + fr;
      bfv[ni] = *(const bf16x8*)((char*)KVs + swz(row * 128 + kk * 64 + fg * 16, row));
    }
#pragma unroll
    for (int mi = 0; mi < 2; ++mi)
#pragma unroll
      for (int ni = 0; ni < 4; ++ni)
        acc[mi][ni] = __builtin_amdgcn_mfma_f32_16x16x32_bf16(af[mi], bfv[ni], acc[mi][ni], 0, 0, 0);
  }
  __syncthreads();

  const float ks = ksum[b * NHEAD + h];
  u16* AObase = AO + ((size_t)b * Ntok + n0) * DMODEL + h * DK_;
#pragma unroll
  for (int mi = 0; mi < 2; ++mi)
#pragma unroll
    for (int ni = 0; ni < 4; ++ni)
#pragma unroll
      for (int r = 0; r < 4; ++r) {
        int row = wm + mi * 16 + fg * 4 + r;
        int col = ni * 16 + fr;
        float rn = 1.f / (qsl[row] * ks + 1e-6f);
        AObase[(size_t)row * DMODEL + col] = f2bf(acc[mi][ni][r] * rn);
      }
}

extern "C" void kernel_launch(void* const* d_in, const int* in_sizes, int n_in,
                              void* d_out, int out_size, void* d_ws, size_t ws_size,
                              hipStream_t stream) {
  const float* x     = (const float*)d_in[0];
  const float* lto   = (const float*)d_in[1];
  const float* sa_wq = (const float*)d_in[4];
  const float* sa_wk = (const float*)d_in[5];
  const float* sa_wv = (const float*)d_in[6];
  const float* sa_wo = (const float*)d_in[7];
  const float* ca_wq = (const float*)d_in[8];
  const float* ca_wk = (const float*)d_in[9];
  const float* ca_wv = (const float*)d_in[10];
  const float* ca_wo = (const float*)d_in[11];
  const float* ff_w1 = (const float*)d_in[12];
  const float* ff_b1 = (const float*)d_in[13];
  const float* ff_w2 = (const float*)d_in[14];
  const float* ff_b2 = (const float*)d_in[15];
  const float* ln1_a = (const float*)d_in[16];
  const float* ln1_b = (const float*)d_in[17];
  const float* ln2_a = (const float*)d_in[18];
  const float* ln2_b = (const float*)d_in[19];
  const float* ln3_a = (const float*)d_in[20];
  const float* ln3_b = (const float*)d_in[21];
  float* out = (float*)d_out;

  char* wsb = (char*)d_ws;
  auto take = [&](size_t bytes) {
    char* p = wsb;
    wsb += (bytes + 255) & ~(size_t)255;
    return (void*)p;
  };
  u16* SAQT = (u16*)take(2097152);
  u16* SAKT = (u16*)take(2097152);
  u16* SAVT = (u16*)take(2097152);
  u16* SAOT = (u16*)take(2097152);
  u16* CQT  = (u16*)take(2097152);
  u16* CKT  = (u16*)take(2097152);
  u16* CVT  = (u16*)take(2097152);
  u16* COT  = (u16*)take(2097152);
  u16* FW1T = (u16*)take(8388608);
  u16* FW2T = (u16*)take(8388608);
  u16* R1 = (u16*)take(33554432);   // XN -> AO -> caV
  u16* R2 = (u16*)take(33554432);   // K -> Q -> caK -> FF hidden
  u16* R3 = (u16*)take(33554432);   // V -> X1
  u16* S1 = (u16*)take(4194304);    // LTON -> FN
  u16* S2 = (u16*)take(4194304);    // CAQ
  u16* S3 = (u16*)take(4194304);    // CAO
  float* LTO1   = (float*)take(8388608);
  float* KVPART = (float*)take(8388608);
  u16*   KVT    = (u16*)take(1048576);
  float* KPART  = (float*)take(2048);
  float* KSUM   = (float*)take(256);

  const int STOK = BATCH * SEQ;   // 16384
  const int LTOK = BATCH * LSEQ;  // 2048
  dim3 blk(256);

  // ---- weight transpose-convert to bf16 [N,K] ----
  wconv_t_kernel<<<dim3(32, 32), blk, 0, stream>>>(sa_wq, SAQT, 1024, 1024);
  wconv_t_kernel<<<dim3(32, 32), blk, 0, stream>>>(sa_wk, SAKT, 1024, 1024);
  wconv_t_kernel<<<dim3(32, 32), blk, 0, stream>>>(sa_wv, SAVT, 1024, 1024);
  wconv_t_kernel<<<dim3(32, 32), blk, 0, stream>>>(sa_wo, SAOT, 1024, 1024);
  wconv_t_kernel<<<dim3(32, 32), blk, 0, stream>>>(ca_wq, CQT, 1024, 1024);
  wconv_t_kernel<<<dim3(32, 32), blk, 0, stream>>>(ca_wk, CKT, 1024, 1024);
  wconv_t_kernel<<<dim3(32, 32), blk, 0, stream>>>(ca_wv, CVT, 1024, 1024);
  wconv_t_kernel<<<dim3(32, 32), blk, 0, stream>>>(ca_wo, COT, 1024, 1024);
  wconv_t_kernel<<<dim3(128, 32), blk, 0, stream>>>(ff_w1, FW1T, 1024, 4096);
  wconv_t_kernel<<<dim3(32, 128), blk, 0, stream>>>(ff_w2, FW2T, 4096, 1024);

  // ---- Phase A: self attention ----
  ln_kernel<<<STOK, blk, 0, stream>>>(x, ln1_a, ln1_b, R1);
  gemm_bf16<2, false, false, true><<<dim3(8, 128), blk, 0, stream>>>(R1, SAKT, nullptr, nullptr, R2, STOK, 1024, 1024); // K
  gemm_bf16<0, false, false, true><<<dim3(8, 128), blk, 0, stream>>>(R1, SAVT, nullptr, nullptr, R3, STOK, 1024, 1024); // V
  kv_part_kernel<<<dim3(NHEAD, BATCH, NSPLIT), blk, 0, stream>>>(R2, R3, KVPART, KPART, SEQ);
  kv_reduce_kernel<<<64, blk, 0, stream>>>(KVPART, KPART, KVT, KSUM);
  gemm_bf16<2, false, false, true><<<dim3(8, 128), blk, 0, stream>>>(R1, SAQT, nullptr, nullptr, R2, STOK, 1024, 1024); // Q
  qk_mfma_kernel<<<dim3(SEQ / 128, NHEAD, BATCH), blk, 0, stream>>>(R2, KVT, KSUM, R1, SEQ);                            // AO
  gemm_bf16<0, false, true, true><<<dim3(8, 128), blk, 0, stream>>>(R1, SAOT, nullptr, x, R3, STOK, 1024, 1024);        // X1 (bf16)

  // ---- Phase B: cross attention ----
  ln_kernel<<<LTOK, blk, 0, stream>>>(lto, ln2_a, ln2_b, S1);
  gemm_bf16<2, false, false, true><<<dim3(8, 16), blk, 0, stream>>>(S1, CQT, nullptr, nullptr, S2, LTOK, 1024, 1024);   // caQ
  gemm_bf16<2, false, false, true><<<dim3(8, 128), blk, 0, stream>>>(R3, CKT, nullptr, nullptr, R2, STOK, 1024, 1024);  // caK
  gemm_bf16<0, false, false, true><<<dim3(8, 128), blk, 0, stream>>>(R3, CVT, nullptr, nullptr, R1, STOK, 1024, 1024);  // caV
  kv_part_kernel<<<dim3(NHEAD, BATCH, NSPLIT), blk, 0, stream>>>(R2, R1, KVPART, KPART, SEQ);
  kv_reduce_kernel<<<64, blk, 0, stream>>>(KVPART, KPART, KVT, KSUM);
  qk_mfma_kernel<<<dim3(LSEQ / 128, NHEAD, BATCH), blk, 0, stream>>>(S2, KVT, KSUM, S3, LSEQ);                          // CAO
  gemm_bf16<0, false, true, false><<<dim3(8, 16), blk, 0, stream>>>(S3, COT, nullptr, lto, LTO1, LTOK, 1024, 1024);     // LTO1 fp32

  // ---- Phase C: feed forward ----
  ln_kernel<<<LTOK, blk, 0, stream>>>(LTO1, ln3_a, ln3_b, S1);
  gemm_bf16<1, true, false, true><<<dim3(32, 16), blk, 0, stream>>>(S1, FW1T, ff_b1, nullptr, R2, LTOK, 4096, 1024);    // FF hidden
  gemm_bf16<0, true, true, false><<<dim3(8, 16), blk, 0, stream>>>(R2, FW2T, ff_b2, LTO1, out, LTOK, 1024, 4096);       // out
}

// Round 5
// 579.218 us; speedup vs baseline: 9.8349x; 1.1942x over previous
//
#include <hip/hip_runtime.h>
#include <hip/hip_bf16.h>

#define BATCH 4
#define SEQ   4096
#define LSEQ  512
#define DMODEL 1024
#define DFF_  4096
#define NHEAD 16
#define DK_   64
#define NSPLIT 8

typedef __attribute__((ext_vector_type(4))) float f32x4;
typedef __attribute__((ext_vector_type(8))) __bf16 bf16x8;
typedef __attribute__((ext_vector_type(8))) unsigned short ushort8v;
typedef unsigned short u16;

__device__ __forceinline__ u16 f2bf(float f) {
  union { float f; unsigned int u; } c; c.f = f;
  unsigned int u = c.u;
  u += 0x7fffu + ((u >> 16) & 1u);
  return (u16)(u >> 16);
}
__device__ __forceinline__ float bf2f(u16 h) {
  union { unsigned int u; float f; } c; c.u = ((unsigned int)h) << 16;
  return c.f;
}
__device__ __forceinline__ void gload16(const void* g, void* l) {
  __builtin_amdgcn_global_load_lds(
      (const __attribute__((address_space(1))) unsigned int*)g,
      (__attribute__((address_space(3))) unsigned int*)l, 16, 0, 0);
}

// ---------------- LayerNorm (ddof=1) -> bf16 ----------------
__global__ __launch_bounds__(256) void ln_kernel(
    const float* __restrict__ x, const float* __restrict__ alpha,
    const float* __restrict__ beta, u16* __restrict__ y)
{
  int row = blockIdx.x;
  const float* xr = x + (size_t)row * DMODEL;
  u16* yr = y + (size_t)row * DMODEL;
  int t = threadIdx.x;
  float v0 = xr[t], v1 = xr[t + 256], v2 = xr[t + 512], v3 = xr[t + 768];
  float s = v0 + v1 + v2 + v3;
  float ss = v0 * v0 + v1 * v1 + v2 * v2 + v3 * v3;
  for (int off = 32; off >= 1; off >>= 1) {
    s += __shfl_xor(s, off);
    ss += __shfl_xor(ss, off);
  }
  __shared__ float sbuf[4], ssbuf[4];
  int w = t >> 6;
  if ((t & 63) == 0) { sbuf[w] = s; ssbuf[w] = ss; }
  __syncthreads();
  s = sbuf[0] + sbuf[1] + sbuf[2] + sbuf[3];
  ss = ssbuf[0] + ssbuf[1] + ssbuf[2] + ssbuf[3];
  float mean = s * (1.f / DMODEL);
  float var = (ss - mean * mean * DMODEL) * (1.f / (DMODEL - 1));
  var = fmaxf(var, 0.f);
  float inv = 1.f / (sqrtf(var) + 1e-6f);
  yr[t]       = f2bf(alpha[t]       * (v0 - mean) * inv + beta[t]);
  yr[t + 256] = f2bf(alpha[t + 256] * (v1 - mean) * inv + beta[t + 256]);
  yr[t + 512] = f2bf(alpha[t + 512] * (v2 - mean) * inv + beta[t + 512]);
  yr[t + 768] = f2bf(alpha[t + 768] * (v3 - mean) * inv + beta[t + 768]);
}

// ---------------- transpose-convert W[K,N] f32 -> Wt[N,K] bf16 ----------------
__global__ __launch_bounds__(256) void wconv_t_kernel(
    const float* __restrict__ W, u16* __restrict__ Wt, int K, int N)
{
  __shared__ float tile[32][33];
  const int n0 = blockIdx.x * 32, k0 = blockIdx.y * 32;
  const int t = threadIdx.x;
  const int r = t >> 3, c4 = (t & 7) * 4;
  float4 v = *(const float4*)&W[(size_t)(k0 + r) * N + n0 + c4];
  tile[r][c4 + 0] = v.x; tile[r][c4 + 1] = v.y;
  tile[r][c4 + 2] = v.z; tile[r][c4 + 3] = v.w;
  __syncthreads();
  ushort4 o;
  o.x = f2bf(tile[c4 + 0][r]);
  o.y = f2bf(tile[c4 + 1][r]);
  o.z = f2bf(tile[c4 + 2][r]);
  o.w = f2bf(tile[c4 + 3][r]);
  *(ushort4*)&Wt[(size_t)(n0 + r) * K + k0 + c4] = o;
}

// =========== 256x256 8-phase MFMA GEMM (T2+T3+T4+T5), K multiple of 128 ===========
// C = act(A[M,K] @ Bt[N,K]^T (+bias)) (+R).  ACT: 0 none, 1 relu, 2 relu+1e-6.
template <int ACT, bool BIAS, bool RESID, bool OUTBF>
__global__ __launch_bounds__(512, 2) void gemm256(
    const u16* __restrict__ A, const u16* __restrict__ Bt,
    const float* __restrict__ bias, const float* __restrict__ R,
    void* __restrict__ Cout, int M, int N, int K)
{
  __shared__ u16 sh[2][2][256 * 64];  // [buf][0=A,1=B][row*64 + k], XOR-swizzled rows of 128B
  const int t = threadIdx.x;
  const int wid = t >> 6, lane = t & 63;
  const int wr = wid >> 2, wc = wid & 3;      // 2 (M) x 4 (N) wave grid
  const int fr = lane & 15, fg = lane >> 4;

  // bijective XCD swizzle (m204)
  int bid = blockIdx.x;
  {
    const int nwg = gridDim.x;
    int q = nwg >> 3, rmd = nwg & 7;
    int xcd = bid & 7, idx = bid >> 3;
    bid = (xcd < rmd ? xcd * (q + 1) : rmd * (q + 1) + (xcd - rmd) * q) + idx;
  }
  const int nxb = N >> 8;
  const int m0 = (bid / nxb) * 256, n0 = (bid % nxb) * 256;

  // stage one half-tile (128 rows x 64 k) of A or B: linear LDS dest, inverse-swizzled source
  auto stageA = [&](int buf, int h, int kt) {
#pragma unroll
    for (int j = 0; j < 2; ++j) {
      int idx = j * 512 + t;
      int r = idx >> 3;
      int gc = ((idx & 7) * 16) ^ ((r & 7) << 4);
      const char* src = (const char*)(A + (size_t)(m0 + h * 128 + r) * K + kt * 64) + gc;
      char* dst = (char*)&sh[buf][0][0] + h * 16384 + j * 8192 + wid * 1024;
      gload16(src, dst);
    }
  };
  auto stageB = [&](int buf, int h, int kt) {
#pragma unroll
    for (int j = 0; j < 2; ++j) {
      int idx = j * 512 + t;
      int r = idx >> 3;
      int gc = ((idx & 7) * 16) ^ ((r & 7) << 4);
      const char* src = (const char*)(Bt + (size_t)(n0 + h * 128 + r) * K + kt * 64) + gc;
      char* dst = (char*)&sh[buf][1][0] + h * 16384 + j * 8192 + wid * 1024;
      gload16(src, dst);
    }
  };
  // swizzled fragment reads
  auto rdA = [&](int buf, int mi, int kk) -> bf16x8 {
    int r = wr * 128 + mi * 16 + fr;
    int c = (kk * 64 + fg * 16) ^ ((r & 7) << 4);
    return *(const bf16x8*)((const char*)&sh[buf][0][0] + r * 128 + c);
  };
  auto rdB = [&](int buf, int ni, int kk) -> bf16x8 {
    int r = wc * 64 + ni * 16 + fr;
    int c = (kk * 64 + fg * 16) ^ ((r & 7) << 4);
    return *(const bf16x8*)((const char*)&sh[buf][1][0] + r * 128 + c);
  };

  f32x4 acc[8][4] = {};
  bf16x8 bfrag[4][2];

#define PHASE(BUF, Q, STAGE_STMT, VCNT) do {                                          \
    STAGE_STMT;                                                                        \
    bf16x8 a00 = rdA(BUF, (Q)*2, 0),     a01 = rdA(BUF, (Q)*2, 1);                     \
    bf16x8 a10 = rdA(BUF, (Q)*2 + 1, 0), a11 = rdA(BUF, (Q)*2 + 1, 1);                 \
    if ((Q) == 0) {                                                                    \
      _Pragma("unroll") for (int ni = 0; ni < 4; ++ni) {                               \
        bfrag[ni][0] = rdB(BUF, ni, 0); bfrag[ni][1] = rdB(BUF, ni, 1); } }            \
    __builtin_amdgcn_s_barrier();                                                      \
    __builtin_amdgcn_sched_barrier(0);                                                 \
    __builtin_amdgcn_s_setprio(1);                                                     \
    _Pragma("unroll") for (int ni = 0; ni < 4; ++ni) {                                 \
      acc[(Q)*2][ni]     = __builtin_amdgcn_mfma_f32_16x16x32_bf16(a00, bfrag[ni][0], acc[(Q)*2][ni], 0, 0, 0);     \
      acc[(Q)*2][ni]     = __builtin_amdgcn_mfma_f32_16x16x32_bf16(a01, bfrag[ni][1], acc[(Q)*2][ni], 0, 0, 0);     \
      acc[(Q)*2 + 1][ni] = __builtin_amdgcn_mfma_f32_16x16x32_bf16(a10, bfrag[ni][0], acc[(Q)*2 + 1][ni], 0, 0, 0); \
      acc[(Q)*2 + 1][ni] = __builtin_amdgcn_mfma_f32_16x16x32_bf16(a11, bfrag[ni][1], acc[(Q)*2 + 1][ni], 0, 0, 0); } \
    __builtin_amdgcn_s_setprio(0);                                                     \
    if ((VCNT) == 4) { asm volatile("s_waitcnt vmcnt(4)" ::: "memory"); }              \
    else if ((VCNT) == 0) { asm volatile("s_waitcnt vmcnt(0)" ::: "memory"); }         \
    __builtin_amdgcn_sched_barrier(0);                                                 \
    __builtin_amdgcn_s_barrier();                                                      \
    __builtin_amdgcn_sched_barrier(0);                                                 \
  } while (0)

  // prologue: tile0 -> buf0 (A+B), tile1 B -> buf1
  stageA(0, 0, 0); stageA(0, 1, 0);
  stageB(0, 0, 0); stageB(0, 1, 0);
  stageB(1, 0, 1); stageB(1, 1, 1);
  asm volatile("s_waitcnt vmcnt(4)" ::: "memory");
  __builtin_amdgcn_s_barrier();
  __builtin_amdgcn_sched_barrier(0);

  const int NIT = K >> 7;  // iterations, 2 K-tiles each
  for (int i = 0; i < NIT - 1; ++i) {
    const int t1 = 2 * i + 1, s0 = 2 * i + 2, s1 = 2 * i + 3;
    PHASE(0, 0, stageA(1, 0, t1), -1);
    PHASE(0, 1, stageA(1, 1, t1), -1);
    PHASE(0, 2, stageB(0, 0, s0), -1);
    PHASE(0, 3, stageB(0, 1, s0), 4);
    PHASE(1, 0, stageA(0, 0, s0), -1);
    PHASE(1, 1, stageA(0, 1, s0), -1);
    PHASE(1, 2, stageB(1, 0, s1), -1);
    PHASE(1, 3, stageB(1, 1, s1), 4);
  }
  {  // tail iteration: no stages beyond K
    const int t1 = 2 * (NIT - 1) + 1;
    PHASE(0, 0, stageA(1, 0, t1), -1);
    PHASE(0, 1, stageA(1, 1, t1), -1);
    PHASE(0, 2, ((void)0), -1);
    PHASE(0, 3, ((void)0), 0);
    PHASE(1, 0, ((void)0), -1);
    PHASE(1, 1, ((void)0), -1);
    PHASE(1, 2, ((void)0), -1);
    PHASE(1, 3, ((void)0), -1);
  }
#undef PHASE

  float* Cf = (float*)Cout;
  u16* Cb = (u16*)Cout;
#pragma unroll
  for (int mi = 0; mi < 8; ++mi)
#pragma unroll
    for (int ni = 0; ni < 4; ++ni)
#pragma unroll
      for (int r = 0; r < 4; ++r) {
        int row = m0 + wr * 128 + mi * 16 + fg * 4 + r;
        int col = n0 + wc * 64 + ni * 16 + fr;
        float v = acc[mi][ni][r];
        if (BIAS) v += bias[col];
        if (ACT == 1) v = fmaxf(v, 0.f);
        if (ACT == 2) v = fmaxf(v, 0.f) + 1e-6f;
        if (RESID) v += R[(size_t)row * N + col];
        if (OUTBF) Cb[(size_t)row * N + col] = f2bf(v);
        else       Cf[(size_t)row * N + col] = v;
      }
}

// ---------------- 128x128 2-phase MFMA GEMM (small shapes) ----------------
template <int ACT, bool BIAS, bool RESID, bool OUTBF>
__global__ __launch_bounds__(256) void gemm_bf16(
    const u16* __restrict__ A, const u16* __restrict__ Bt,
    const float* __restrict__ bias, const float* __restrict__ R,
    void* __restrict__ Cout, int M, int N, int K)
{
  __shared__ u16 As[2][128 * 32];
  __shared__ u16 Bs[2][128 * 32];
  const int t = threadIdx.x;
  const int m0 = blockIdx.y * 128, n0 = blockIdx.x * 128;
  const int lane = t & 63, wid = t >> 6;
  const int wm = (wid >> 1) * 64, wn = (wid & 1) * 64;
  const int fr = lane & 15, fg = lane >> 4;

  const int srow = t >> 2;
  const int scol = (t & 3) * 8;
  const u16* aptr = A + (size_t)(m0 + srow) * K + scol;
  const u16* bptr = Bt + (size_t)(n0 + srow) * K + scol;
  const size_t rstep = (size_t)64 * K;

  f32x4 acc[4][4] = {};

  auto stage = [&](int c, int k0) {
    gload16(aptr + k0,         &As[c][wid * 512]);
    gload16(aptr + k0 + rstep, &As[c][2048 + wid * 512]);
    gload16(bptr + k0,         &Bs[c][wid * 512]);
    gload16(bptr + k0 + rstep, &Bs[c][2048 + wid * 512]);
  };
  auto compute = [&](int c) {
    bf16x8 af[4], bfr[4];
#pragma unroll
    for (int mi = 0; mi < 4; ++mi)
      af[mi] = *(const bf16x8*)&As[c][(wm + mi * 16 + fr) * 32 + fg * 8];
#pragma unroll
    for (int ni = 0; ni < 4; ++ni)
      bfr[ni] = *(const bf16x8*)&Bs[c][(wn + ni * 16 + fr) * 32 + fg * 8];
#pragma unroll
    for (int mi = 0; mi < 4; ++mi)
#pragma unroll
      for (int ni = 0; ni < 4; ++ni)
        acc[mi][ni] = __builtin_amdgcn_mfma_f32_16x16x32_bf16(af[mi], bfr[ni], acc[mi][ni], 0, 0, 0);
  };

  const int NT = K >> 5;
  stage(0, 0);
  asm volatile("s_waitcnt vmcnt(0)" ::: "memory");
  __builtin_amdgcn_s_barrier();
  int cur = 0;
  for (int kt = 0; kt < NT - 1; ++kt) {
    stage(cur ^ 1, (kt + 1) * 32);
    compute(cur);
    asm volatile("s_waitcnt vmcnt(0)" ::: "memory");
    __builtin_amdgcn_s_barrier();
    cur ^= 1;
  }
  compute(cur);

  float* Cf = (float*)Cout;
  u16* Cb = (u16*)Cout;
#pragma unroll
  for (int mi = 0; mi < 4; ++mi)
#pragma unroll
    for (int ni = 0; ni < 4; ++ni)
#pragma unroll
      for (int r = 0; r < 4; ++r) {
        int row = m0 + wm + mi * 16 + fg * 4 + r;
        int col = n0 + wn + ni * 16 + fr;
        float v = acc[mi][ni][r];
        if (BIAS) v += bias[col];
        if (ACT == 1) v = fmaxf(v, 0.f);
        if (ACT == 2) v = fmaxf(v, 0.f) + 1e-6f;
        if (RESID) v += R[(size_t)row * N + col];
        if (OUTBF) Cb[(size_t)row * N + col] = f2bf(v);
        else       Cf[(size_t)row * N + col] = v;
      }
}

// ---------------- partial KV state over an n-chunk (bf16 in, f32 out) ----------------
__global__ __launch_bounds__(256) void kv_part_kernel(
    const u16* __restrict__ Kp, const u16* __restrict__ Vp,
    float* __restrict__ kvpart, float* __restrict__ kpart, int Ntok)
{
  const int h = blockIdx.x, b = blockIdx.y, sp = blockIdx.z;
  const int rows = Ntok / NSPLIT;
  const int nbeg = sp * rows;
  const u16* Kb = Kp + ((size_t)b * Ntok + nbeg) * DMODEL + h * DK_;
  const u16* Vb = Vp + ((size_t)b * Ntok + nbeg) * DMODEL + h * DK_;
  __shared__ float Ks[64][65];
  __shared__ float Vs[64][65];
  const int t = threadIdx.x;
  const int tx = t & 15, ty = t >> 4;
  const int lr = t >> 3;
  const int lc = (t & 7) * 8;
  float acc[4][4] = {};
  float kp = 0.f;
  for (int n0 = 0; n0 < rows; n0 += 64) {
#pragma unroll
    for (int p = 0; p < 2; ++p) {
      int r = p * 32 + lr;
      ushort8v k8 = *(const ushort8v*)&Kb[(size_t)(n0 + r) * DMODEL + lc];
      ushort8v v8 = *(const ushort8v*)&Vb[(size_t)(n0 + r) * DMODEL + lc];
#pragma unroll
      for (int i = 0; i < 8; ++i) {
        float kf = bf2f(k8[i]);
        Ks[r][lc + i] = kf;
        kp += kf;
        Vs[r][lc + i] = bf2f(v8[i]);
      }
    }
    __syncthreads();
    for (int nn = 0; nn < 64; ++nn) {
      float a[4], bb[4];
#pragma unroll
      for (int i = 0; i < 4; ++i) a[i] = Ks[nn][ty * 4 + i];
#pragma unroll
      for (int j = 0; j < 4; ++j) bb[j] = Vs[nn][tx * 4 + j];
#pragma unroll
      for (int i = 0; i < 4; ++i)
#pragma unroll
        for (int j = 0; j < 4; ++j) acc[i][j] += a[i] * bb[j];
    }
    __syncthreads();
  }
  float* outp = kvpart + (((size_t)(b * NHEAD + h)) * NSPLIT + sp) * (DK_ * DK_);
#pragma unroll
  for (int i = 0; i < 4; ++i)
#pragma unroll
    for (int j = 0; j < 4; ++j)
      outp[(ty * 4 + i) * DK_ + tx * 4 + j] = acc[i][j];
  for (int off = 32; off >= 1; off >>= 1) kp += __shfl_xor(kp, off);
  __shared__ float kr[4];
  if ((t & 63) == 0) kr[t >> 6] = kp;
  __syncthreads();
  if (t == 0) kpart[(b * NHEAD + h) * NSPLIT + sp] = kr[0] + kr[1] + kr[2] + kr[3];
}

// reduce partials -> kv^T bf16 [e][d] + ksum
__global__ __launch_bounds__(256) void kv_reduce_kernel(
    const float* __restrict__ kvpart, const float* __restrict__ kpart,
    u16* __restrict__ kvT, float* __restrict__ ksum)
{
  const int bh = blockIdx.x;
  const int t = threadIdx.x;
  for (int i = t; i < DK_ * DK_; i += 256) {
    int d = i >> 6, e = i & 63;
    float s = 0.f;
#pragma unroll
    for (int p = 0; p < NSPLIT; ++p)
      s += kvpart[((size_t)bh * NSPLIT + p) * (DK_ * DK_) + i];
    kvT[(size_t)bh * (DK_ * DK_) + e * DK_ + d] = f2bf(s);
  }
  if (t == 0) {
    float s = 0.f;
    for (int p = 0; p < NSPLIT; ++p) s += kpart[bh * NSPLIT + p];
    ksum[bh] = s;
  }
}

// ---------------- AO = (Q @ kv) * 1/(qsum*ksum+1e-6) via MFMA ----------------
__global__ __launch_bounds__(256) void qk_mfma_kernel(
    const u16* __restrict__ Qp, const u16* __restrict__ kvT,
    const float* __restrict__ ksum, u16* __restrict__ AO, int Ntok)
{
  const int h = blockIdx.y, b = blockIdx.z;
  const int n0 = blockIdx.x * 128;
  const int t = threadIdx.x;
  const int lane = t & 63, wid = t >> 6;
  const int fr = lane & 15, fg = lane >> 4;

  __shared__ u16 Qs[128 * 64];
  __shared__ u16 KVs[64 * 64];
  __shared__ float qsl[128];

  auto swz = [](int byte, int row) { return byte ^ ((row & 7) << 4); };

  const u16* Qbase = Qp + ((size_t)b * Ntok + n0) * DMODEL + h * DK_;
#pragma unroll
  for (int j = 0; j < 4; ++j) {
    int id = t + 256 * j;
    int r = id >> 3, cseg = id & 7;
    ushort8v v = *(const ushort8v*)(Qbase + (size_t)r * DMODEL + cseg * 8);
    *(ushort8v*)((char*)Qs + swz(r * 128 + cseg * 16, r)) = v;
  }
  const u16* Kbase = kvT + ((size_t)(b * NHEAD + h)) * (DK_ * DK_);
#pragma unroll
  for (int j = 0; j < 2; ++j) {
    int id = t + 256 * j;
    int r = id >> 3, cseg = id & 7;
    ushort8v v = *(const ushort8v*)(Kbase + r * DK_ + cseg * 8);
    *(ushort8v*)((char*)KVs + swz(r * 128 + cseg * 16, r)) = v;
  }
  __syncthreads();

  {
    int row = t >> 1, part = t & 1;
    float s = 0.f;
#pragma unroll
    for (int j = 0; j < 4; ++j) {
      bf16x8 v = *(const bf16x8*)((char*)Qs + swz(row * 128 + (part * 4 + j) * 16, row));
#pragma unroll
      for (int i = 0; i < 8; ++i) s += (float)v[i];
    }
    s += __shfl_xor(s, 1);
    if (part == 0) qsl[row] = s;
  }

  const int wm = wid * 32;
  f32x4 acc[2][4] = {};
#pragma unroll
  for (int kk = 0; kk < 2; ++kk) {
    bf16x8 af[2], bfv[4];
#pragma unroll
    for (int mi = 0; mi < 2; ++mi) {
      int row = wm + mi * 16 + fr;
      af[mi] = *(const bf16x8*)((char*)Qs + swz(row * 128 + kk * 64 + fg * 16, row));
    }
#pragma unroll
    for (int ni = 0; ni < 4; ++ni) {
      int row = ni * 16 + fr;
      bfv[ni] = *(const bf16x8*)((char*)KVs + swz(row * 128 + kk * 64 + fg * 16, row));
    }
#pragma unroll
    for (int mi = 0; mi < 2; ++mi)
#pragma unroll
      for (int ni = 0; ni < 4; ++ni)
        acc[mi][ni] = __builtin_amdgcn_mfma_f32_16x16x32_bf16(af[mi], bfv[ni], acc[mi][ni], 0, 0, 0);
  }
  __syncthreads();

  const float ks = ksum[b * NHEAD + h];
  u16* AObase = AO + ((size_t)b * Ntok + n0) * DMODEL + h * DK_;
#pragma unroll
  for (int mi = 0; mi < 2; ++mi)
#pragma unroll
    for (int ni = 0; ni < 4; ++ni)
#pragma unroll
      for (int r = 0; r < 4; ++r) {
        int row = wm + mi * 16 + fg * 4 + r;
        int col = ni * 16 + fr;
        float rn = 1.f / (qsl[row] * ks + 1e-6f);
        AObase[(size_t)row * DMODEL + col] = f2bf(acc[mi][ni][r] * rn);
      }
}

extern "C" void kernel_launch(void* const* d_in, const int* in_sizes, int n_in,
                              void* d_out, int out_size, void* d_ws, size_t ws_size,
                              hipStream_t stream) {
  const float* x     = (const float*)d_in[0];
  const float* lto   = (const float*)d_in[1];
  const float* sa_wq = (const float*)d_in[4];
  const float* sa_wk = (const float*)d_in[5];
  const float* sa_wv = (const float*)d_in[6];
  const float* sa_wo = (const float*)d_in[7];
  const float* ca_wq = (const float*)d_in[8];
  const float* ca_wk = (const float*)d_in[9];
  const float* ca_wv = (const float*)d_in[10];
  const float* ca_wo = (const float*)d_in[11];
  const float* ff_w1 = (const float*)d_in[12];
  const float* ff_b1 = (const float*)d_in[13];
  const float* ff_w2 = (const float*)d_in[14];
  const float* ff_b2 = (const float*)d_in[15];
  const float* ln1_a = (const float*)d_in[16];
  const float* ln1_b = (const float*)d_in[17];
  const float* ln2_a = (const float*)d_in[18];
  const float* ln2_b = (const float*)d_in[19];
  const float* ln3_a = (const float*)d_in[20];
  const float* ln3_b = (const float*)d_in[21];
  float* out = (float*)d_out;

  char* wsb = (char*)d_ws;
  auto take = [&](size_t bytes) {
    char* p = wsb;
    wsb += (bytes + 255) & ~(size_t)255;
    return (void*)p;
  };
  u16* SAQT = (u16*)take(2097152);
  u16* SAKT = (u16*)take(2097152);
  u16* SAVT = (u16*)take(2097152);
  u16* SAOT = (u16*)take(2097152);
  u16* CQT  = (u16*)take(2097152);
  u16* CKT  = (u16*)take(2097152);
  u16* CVT  = (u16*)take(2097152);
  u16* COT  = (u16*)take(2097152);
  u16* FW1T = (u16*)take(8388608);
  u16* FW2T = (u16*)take(8388608);
  u16* R1 = (u16*)take(33554432);   // XN -> AO -> caV
  u16* R2 = (u16*)take(33554432);   // K -> Q -> caK -> FF hidden
  u16* R3 = (u16*)take(33554432);   // V -> X1
  u16* S1 = (u16*)take(4194304);    // LTON -> FN
  u16* S2 = (u16*)take(4194304);    // CAQ
  u16* S3 = (u16*)take(4194304);    // CAO
  float* LTO1   = (float*)take(8388608);
  float* KVPART = (float*)take(8388608);
  u16*   KVT    = (u16*)take(1048576);
  float* KPART  = (float*)take(2048);
  float* KSUM   = (float*)take(256);

  const int STOK = BATCH * SEQ;   // 16384
  const int LTOK = BATCH * LSEQ;  // 2048
  dim3 blk(256);
  dim3 blk512(512);
  dim3 gbig(STOK / 256 * (DMODEL / 256));  // 64*4 = 256 blocks

  // ---- weight transpose-convert to bf16 [N,K] ----
  wconv_t_kernel<<<dim3(32, 32), blk, 0, stream>>>(sa_wq, SAQT, 1024, 1024);
  wconv_t_kernel<<<dim3(32, 32), blk, 0, stream>>>(sa_wk, SAKT, 1024, 1024);
  wconv_t_kernel<<<dim3(32, 32), blk, 0, stream>>>(sa_wv, SAVT, 1024, 1024);
  wconv_t_kernel<<<dim3(32, 32), blk, 0, stream>>>(sa_wo, SAOT, 1024, 1024);
  wconv_t_kernel<<<dim3(32, 32), blk, 0, stream>>>(ca_wq, CQT, 1024, 1024);
  wconv_t_kernel<<<dim3(32, 32), blk, 0, stream>>>(ca_wk, CKT, 1024, 1024);
  wconv_t_kernel<<<dim3(32, 32), blk, 0, stream>>>(ca_wv, CVT, 1024, 1024);
  wconv_t_kernel<<<dim3(32, 32), blk, 0, stream>>>(ca_wo, COT, 1024, 1024);
  wconv_t_kernel<<<dim3(128, 32), blk, 0, stream>>>(ff_w1, FW1T, 1024, 4096);
  wconv_t_kernel<<<dim3(32, 128), blk, 0, stream>>>(ff_w2, FW2T, 4096, 1024);

  // ---- Phase A: self attention ----
  ln_kernel<<<STOK, blk, 0, stream>>>(x, ln1_a, ln1_b, R1);
  gemm256<2, false, false, true><<<gbig, blk512, 0, stream>>>(R1, SAKT, nullptr, nullptr, R2, STOK, 1024, 1024); // K
  gemm256<0, false, false, true><<<gbig, blk512, 0, stream>>>(R1, SAVT, nullptr, nullptr, R3, STOK, 1024, 1024); // V
  kv_part_kernel<<<dim3(NHEAD, BATCH, NSPLIT), blk, 0, stream>>>(R2, R3, KVPART, KPART, SEQ);
  kv_reduce_kernel<<<64, blk, 0, stream>>>(KVPART, KPART, KVT, KSUM);
  gemm256<2, false, false, true><<<gbig, blk512, 0, stream>>>(R1, SAQT, nullptr, nullptr, R2, STOK, 1024, 1024); // Q
  qk_mfma_kernel<<<dim3(SEQ / 128, NHEAD, BATCH), blk, 0, stream>>>(R2, KVT, KSUM, R1, SEQ);                     // AO
  gemm256<0, false, true, true><<<gbig, blk512, 0, stream>>>(R1, SAOT, nullptr, x, R3, STOK, 1024, 1024);        // X1

  // ---- Phase B: cross attention ----
  ln_kernel<<<LTOK, blk, 0, stream>>>(lto, ln2_a, ln2_b, S1);
  gemm_bf16<2, false, false, true><<<dim3(8, 16), blk, 0, stream>>>(S1, CQT, nullptr, nullptr, S2, LTOK, 1024, 1024);   // caQ
  gemm256<2, false, false, true><<<gbig, blk512, 0, stream>>>(R3, CKT, nullptr, nullptr, R2, STOK, 1024, 1024);  // caK
  gemm256<0, false, false, true><<<gbig, blk512, 0, stream>>>(R3, CVT, nullptr, nullptr, R1, STOK, 1024, 1024);  // caV
  kv_part_kernel<<<dim3(NHEAD, BATCH, NSPLIT), blk, 0, stream>>>(R2, R1, KVPART, KPART, SEQ);
  kv_reduce_kernel<<<64, blk, 0, stream>>>(KVPART, KPART, KVT, KSUM);
  qk_mfma_kernel<<<dim3(LSEQ / 128, NHEAD, BATCH), blk, 0, stream>>>(S2, KVT, KSUM, S3, LSEQ);                          // CAO
  gemm_bf16<0, false, true, false><<<dim3(8, 16), blk, 0, stream>>>(S3, COT, nullptr, lto, LTO1, LTOK, 1024, 1024);     // LTO1 fp32

  // ---- Phase C: feed forward ----
  ln_kernel<<<LTOK, blk, 0, stream>>>(LTO1, ln3_a, ln3_b, S1);
  gemm_bf16<1, true, false, true><<<dim3(32, 16), blk, 0, stream>>>(S1, FW1T, ff_b1, nullptr, R2, LTOK, 4096, 1024);    // FF hidden
  gemm_bf16<0, true, true, false><<<dim3(8, 16), blk, 0, stream>>>(R2, FW2T, ff_b2, LTO1, out, LTOK, 1024, 4096);       // out
}